// Round 21
// baseline (826.501 us; speedup 1.0000x reference)
//
#include <hip/hip_runtime.h>
#include <hip/hip_bf16.h>

constexpr int B   = 4;
constexpr int N   = 1024;
constexpr int D   = 128;
constexpr int KNN = 10;
constexpr int NH  = 4;

typedef _Float16 half2v __attribute__((ext_vector_type(2)));
typedef _Float16 f16x4  __attribute__((ext_vector_type(4)));
typedef _Float16 f16x8  __attribute__((ext_vector_type(8)));
typedef float    f32x4  __attribute__((ext_vector_type(4)));

static __device__ __forceinline__ half2v pkrtz(float a, float b) {
  return __builtin_bit_cast(half2v, __builtin_amdgcn_cvt_pkrtz(a, b));
}
static __device__ __forceinline__ float h2f(half2v h) {
  return __builtin_bit_cast(float, h);
}

// ---------------------------------------------------------------- norm p2d
__global__ __launch_bounds__(256) void k_norm2d(const float* __restrict__ p2d,
                                                float* __restrict__ f2) {
  int i = blockIdx.x * 256 + threadIdx.x;  // over B*N
  const float* p = p2d + (size_t)i * 3;
  float x = p[0], y = p[1], z = p[2];
  float inr = 1.f / sqrtf(x * x + y * y + z * z);
  float* o = f2 + (size_t)i * 3;
  o[0] = x * inr; o[1] = y * inr; o[2] = z * inr;
}

// ---------------------------------------------------------------- merge-fold precompute
// wcomb[i][o][0:128]   = mlp1_w[i][o][0:128]
// wcomb[i][o][128+c]   = sum_k mlp1_w[i][o][128+k] * merge_w[i][k][c]
// bcomb[i][o]          = mlp1_b[i][o] + sum_k mlp1_w[i][o][128+k] * merge_b[i][k]
// (h = W1a*desc + W1b*(Wm*attn + bm) + b1 — linear identity, merge GEMM removed)
__global__ __launch_bounds__(128) void k_fold(const float* __restrict__ mlp1_w,
                                              const float* __restrict__ mlp1_b,
                                              const float* __restrict__ merge_w,
                                              const float* __restrict__ merge_b,
                                              float* __restrict__ wcomb,
                                              float* __restrict__ bcomb) {
  __shared__ float red[128];
  const int o = blockIdx.x;        // 0..255
  const int i = blockIdx.y;        // layer 0..5
  const int c = threadIdx.x;       // 0..127
  const float* W1 = mlp1_w + (size_t)i * 256 * 256 + (size_t)o * 256;
  const float* Wm = merge_w + (size_t)i * 128 * 128;
  float* out = wcomb + (size_t)i * 256 * 256 + (size_t)o * 256;
  out[c] = W1[c];
  float acc = 0.f;
#pragma unroll 8
  for (int k = 0; k < 128; ++k)
    acc = fmaf(W1[128 + k], Wm[(size_t)k * 128 + c], acc);
  out[128 + c] = acc;
  red[c] = W1[128 + c] * merge_b[i * 128 + c];
  __syncthreads();
  for (int s = 64; s > 0; s >>= 1) {
    if (c < s) red[c] += red[c + s];
    __syncthreads();
  }
  if (c == 0) bcomb[i * 256 + o] = mlp1_b[i * 256 + o] + red[0];
}

// ---------------------------------------------------------------- KNN encode v2: wave-per-query (R17, validated)
__global__ __launch_bounds__(256) void k_encode(const float* __restrict__ pts,
                                                const float* __restrict__ w,
                                                const float* __restrict__ bias,
                                                float* __restrict__ desc) {
  __shared__ float Px[N], Py[N], Pz[N], Xx[N];
  const int t = threadIdx.x;
  const int l = t & 63, wv = t >> 6;
  const int n = blockIdx.x * 4 + wv;
  const int b = blockIdx.y;
  const float* pb = pts + (size_t)b * N * 3;
  for (int i = t; i < N; i += 256) {
    float x = pb[i * 3 + 0], y = pb[i * 3 + 1], z = pb[i * 3 + 2];
    Px[i] = x; Py[i] = y; Pz[i] = z;
    Xx[i] = x * x + y * y + z * z;
  }
  __syncthreads();
  const float cx = Px[n], cy = Py[n], cz = Pz[n], cxx = Xx[n];
  float dist[16];
#pragma unroll
  for (int i = 0; i < 16; ++i) {
    int j = i * 64 + l;
    float ip = cx * Px[j] + cy * Py[j] + cz * Pz[j];
    dist[i] = 2.f * ip - cxx - Xx[j];
  }
  float sx = 0.f, sy = 0.f, sz = 0.f;
#pragma unroll
  for (int kk = 0; kk < KNN; ++kk) {
    float bv = dist[0]; int bi = l;
#pragma unroll
    for (int i = 1; i < 16; ++i) {
      if (dist[i] > bv) { bv = dist[i]; bi = i * 64 + l; }
    }
#pragma unroll
    for (int sft = 1; sft < 64; sft <<= 1) {
      float v2 = __shfl_xor(bv, sft, 64);
      int   i2 = __shfl_xor(bi, sft, 64);
      if (v2 > bv || (v2 == bv && i2 < bi)) { bv = v2; bi = i2; }
    }
    sx += Px[bi]; sy += Py[bi]; sz += Pz[bi];
    if ((bi & 63) == l) {
      int io = bi >> 6;
#pragma unroll
      for (int i = 0; i < 16; ++i)
        if (i == io) dist[i] = -3.0e38f;
    }
  }
  const float invk = 1.f / KNN;
  float feat[6];
  feat[0] = sx * invk - cx; feat[1] = sy * invk - cy; feat[2] = sz * invk - cz;
  feat[3] = cx; feat[4] = cy; feat[5] = cz;
#pragma unroll
  for (int rep = 0; rep < 2; ++rep) {
    int c = rep * 64 + l;
    const float* wr = w + c * 6;
    float a = bias[c];
#pragma unroll
    for (int j = 0; j < 6; ++j) a += wr[j] * feat[j];
    desc[((size_t)b * D + c) * N + n] = a;
  }
}

// ---------------------------------------------------------------- tiled GEMM conv v3: MFMA f16 (R15, validated)
__global__ __launch_bounds__(256) void k_gemm(
    const float* __restrict__ pA0, const float* __restrict__ pA1,
    const float* __restrict__ pB0, const float* __restrict__ pB1,
    const float* __restrict__ w, const float* __restrict__ bias,
    const float* __restrict__ res, float* __restrict__ out,
    const float* __restrict__ stat, const float* __restrict__ g,
    const float* __restrict__ bt,
    int Cin, int catOff, size_t a_bstr, size_t b_bstr,
    int segCout, size_t segStride, int qkvMode) {
  __shared__ _Float16 As[64][48];
  __shared__ half2v   Bs[16][132];
  __shared__ float Ac[256], Bc[256];
  const int tid = threadIdx.x;
  const int wv  = tid >> 6;
  const int l   = tid & 63;
  const int wo  = wv >> 1;
  const int wn  = wv & 1;
  const int lr  = l & 15;
  const int lg  = l >> 4;
  const int o0 = blockIdx.y * 64;
  const int zb = blockIdx.x;
  const int z  = zb >> 3;
  const int n0 = (zb & 7) * 128;
  const int s = z >> 2, b = z & 3;
  const int seg = o0 / segCout;
  const int oo  = o0 % segCout;

  const float* XA = (s ? pA1 : pA0) + (size_t)b * a_bstr;
  const float* XB = pB0 ? ((s ? pB1 : pB0) + (size_t)b * b_bstr) : nullptr;
  const bool segB = qkvMode && (seg > 0);

  if (stat) {
    const float* st = stat + (size_t)s * 256 * 2;
    float A = st[tid * 2 + 1] * g[tid];
    Ac[tid] = A;
    Bc[tid] = fmaf(-st[tid * 2 + 0], A, bt[tid]);
  }

  f32x4 acc[2][4];
#pragma unroll
  for (int i = 0; i < 2; ++i)
#pragma unroll
    for (int j = 0; j < 4; ++j) acc[i][j] = (f32x4){0.f, 0.f, 0.f, 0.f};

  for (int kb = 0; kb < Cin; kb += 32) {
    __syncthreads();
#pragma unroll
    for (int j = 0; j < 2; ++j) {
      int idx = j * 256 + tid;
      int o = idx >> 3, c4 = (idx & 7) * 4;
      float4 wvv = *(const float4*)&w[(size_t)(o0 + o) * Cin + kb + c4];
      *(half2v*)&As[o][c4]     = pkrtz(wvv.x, wvv.y);
      *(half2v*)&As[o][c4 + 2] = pkrtz(wvv.z, wvv.w);
    }
#pragma unroll
    for (int j = 0; j < 2; ++j) {
      int idx = j * 256 + tid;
      int rp = idx >> 5, c4 = (idx & 31) * 4;
      int c0 = kb + 2 * rp, c1 = c0 + 1;
      const float* s0; int cc0 = c0;
      const float* s1; int cc1 = c1;
      if (qkvMode) {
        s0 = segB ? XB : XA; s1 = s0;
      } else {
        if (c0 >= catOff) { s0 = XB; cc0 = c0 - catOff; } else s0 = XA;
        if (c1 >= catOff) { s1 = XB; cc1 = c1 - catOff; } else s1 = XA;
      }
      float4 v0 = *(const float4*)&s0[(size_t)cc0 * N + n0 + c4];
      float4 v1 = *(const float4*)&s1[(size_t)cc1 * N + n0 + c4];
      if (stat) {
        float A0 = Ac[c0], B0 = Bc[c0], A1 = Ac[c1], B1 = Bc[c1];
        v0.x = fmaxf(fmaf(v0.x, A0, B0), 0.f);
        v0.y = fmaxf(fmaf(v0.y, A0, B0), 0.f);
        v0.z = fmaxf(fmaf(v0.z, A0, B0), 0.f);
        v0.w = fmaxf(fmaf(v0.w, A0, B0), 0.f);
        v1.x = fmaxf(fmaf(v1.x, A1, B1), 0.f);
        v1.y = fmaxf(fmaf(v1.y, A1, B1), 0.f);
        v1.z = fmaxf(fmaf(v1.z, A1, B1), 0.f);
        v1.w = fmaxf(fmaf(v1.w, A1, B1), 0.f);
      }
      float4 packed;
      packed.x = h2f(pkrtz(v0.x, v1.x));
      packed.y = h2f(pkrtz(v0.y, v1.y));
      packed.z = h2f(pkrtz(v0.z, v1.z));
      packed.w = h2f(pkrtz(v0.w, v1.w));
      *(float4*)&Bs[rp][c4] = packed;
    }
    __syncthreads();
    f16x8 afr0 = *(const f16x8*)&As[wo * 32 + lr][lg * 8];
    f16x8 afr1 = *(const f16x8*)&As[wo * 32 + 16 + lr][lg * 8];
#pragma unroll
    for (int tj = 0; tj < 4; ++tj) {
      int nn = wn * 64 + tj * 16 + lr;
      float4 btmp;
      btmp.x = *(const float*)&Bs[lg * 4 + 0][nn];
      btmp.y = *(const float*)&Bs[lg * 4 + 1][nn];
      btmp.z = *(const float*)&Bs[lg * 4 + 2][nn];
      btmp.w = *(const float*)&Bs[lg * 4 + 3][nn];
      f16x8 bfr = __builtin_bit_cast(f16x8, btmp);
      acc[0][tj] = __builtin_amdgcn_mfma_f32_16x16x32_f16(afr0, bfr, acc[0][tj], 0, 0, 0);
      acc[1][tj] = __builtin_amdgcn_mfma_f32_16x16x32_f16(afr1, bfr, acc[1][tj], 0, 0, 0);
    }
  }
#pragma unroll
  for (int ti = 0; ti < 2; ++ti) {
#pragma unroll
    for (int tj = 0; tj < 4; ++tj) {
      int nn = n0 + wn * 64 + tj * 16 + lr;
#pragma unroll
      for (int r = 0; r < 4; ++r) {
        int lrow = wo * 32 + ti * 16 + lg * 4 + r;
        size_t ob = (size_t)seg * segStride +
                    ((size_t)z * segCout + oo + lrow) * N + nn;
        float v = acc[ti][tj][r] + bias[o0 + lrow];
        if (res) v += res[ob];
        out[ob] = v;
      }
    }
  }
}

// ---------------------------------------------------------------- attention v10: MFMA flash (R16, validated)
__global__ __launch_bounds__(512) void k_attn(const float* __restrict__ Q,
                                              const float* __restrict__ Kt,
                                              const float* __restrict__ Vt,
                                              float* __restrict__ O) {
  __shared__ _Float16 Klds[128][40];
  __shared__ _Float16 Vlds[32][136];
  const int t  = threadIdx.x;
  const int l  = t & 63, w = t >> 6;
  const int lr = l & 15, lg = l >> 4;
  const int q0 = blockIdx.x * 128 + w * 16;
  const int h  = blockIdx.y;
  const int z  = blockIdx.z;
  const size_t base = (size_t)z * (size_t)(D * N);
  const float* Kg = Kt + base + (size_t)h * N;
  const float* Vg = Vt + base + (size_t)h * N;
  const float scale = 0.17677669529663687f;

  f16x8 qfrag;
  {
    float qv[8];
#pragma unroll
    for (int j = 0; j < 8; ++j)
      qv[j] = Q[base + (size_t)((lg * 8 + j) * 4 + h) * N + q0 + lr] * scale;
    float4 qp;
    qp.x = h2f(pkrtz(qv[0], qv[1]));
    qp.y = h2f(pkrtz(qv[2], qv[3]));
    qp.z = h2f(pkrtz(qv[4], qv[5]));
    qp.w = h2f(pkrtz(qv[6], qv[7]));
    qfrag = __builtin_bit_cast(f16x8, qp);
  }

  f32x4 oacc0 = (f32x4){0.f, 0.f, 0.f, 0.f};
  f32x4 oacc1 = (f32x4){0.f, 0.f, 0.f, 0.f};
  float m = -1e30f, lsum = 0.f;

  for (int c = 0; c < 8; ++c) {
    const int k0 = c * 128;
    __syncthreads();
    {
      int kk = t & 127, d0 = (t >> 7) * 8;
      float kv[8];
#pragma unroll
      for (int j = 0; j < 8; ++j)
        kv[j] = Kg[(size_t)((d0 + j) * 4) * N + k0 + kk];
      float4 pk;
      pk.x = h2f(pkrtz(kv[0], kv[1]));
      pk.y = h2f(pkrtz(kv[2], kv[3]));
      pk.z = h2f(pkrtz(kv[4], kv[5]));
      pk.w = h2f(pkrtz(kv[6], kv[7]));
      *(float4*)&Klds[kk][d0] = pk;
      int dv = t & 31, ko = (t >> 5) * 8;
      const float* vp = Vg + (size_t)(dv * 4) * N + k0 + ko;
      float4 v0 = *(const float4*)vp;
      float4 v1 = *(const float4*)(vp + 4);
      float4 pv;
      pv.x = h2f(pkrtz(v0.x, v0.y)); pv.y = h2f(pkrtz(v0.z, v0.w));
      pv.z = h2f(pkrtz(v1.x, v1.y)); pv.w = h2f(pkrtz(v1.z, v1.w));
      *(float4*)&Vlds[dv][ko] = pv;
    }
    __syncthreads();
#pragma unroll
    for (int kt = 0; kt < 8; ++kt) {
      f16x8 kfrag = *(const f16x8*)&Klds[kt * 16 + lr][lg * 8];
      f32x4 s = __builtin_amdgcn_mfma_f32_16x16x32_f16(
          kfrag, qfrag, (f32x4){0.f, 0.f, 0.f, 0.f}, 0, 0, 0);
      float tmax = fmaxf(fmaxf(s[0], s[1]), fmaxf(s[2], s[3]));
      tmax = fmaxf(tmax, __shfl_xor(tmax, 16, 64));
      tmax = fmaxf(tmax, __shfl_xor(tmax, 32, 64));
      float nm = fmaxf(m, tmax);
      float corr = __expf(m - nm);
      m = nm;
      lsum *= corr;
#pragma unroll
      for (int r = 0; r < 4; ++r) { oacc0[r] *= corr; oacc1[r] *= corr; }
      float p0 = __expf(s[0] - m), p1 = __expf(s[1] - m);
      float p2 = __expf(s[2] - m), p3 = __expf(s[3] - m);
      float ts = p0 + p1 + p2 + p3;
      ts += __shfl_xor(ts, 16, 64);
      ts += __shfl_xor(ts, 32, 64);
      lsum += ts;
      float2 ptmp;
      ptmp.x = h2f(pkrtz(p0, p1));
      ptmp.y = h2f(pkrtz(p2, p3));
      f16x4 pfrag = __builtin_bit_cast(f16x4, ptmp);
      float2 vt0 = *(const float2*)&Vlds[lr][kt * 16 + lg * 4];
      float2 vt1 = *(const float2*)&Vlds[16 + lr][kt * 16 + lg * 4];
      f16x4 vf0 = __builtin_bit_cast(f16x4, vt0);
      f16x4 vf1 = __builtin_bit_cast(f16x4, vt1);
      oacc0 = __builtin_amdgcn_mfma_f32_16x16x16f16(vf0, pfrag, oacc0, 0, 0, 0);
      oacc1 = __builtin_amdgcn_mfma_f32_16x16x16f16(vf1, pfrag, oacc1, 0, 0, 0);
    }
  }
  float invL = 1.f / lsum;
#pragma unroll
  for (int r = 0; r < 4; ++r) {
    int d0 = lg * 4 + r;
    O[base + (size_t)(d0 * 4 + h) * N + q0 + lr] = oacc0[r] * invL;
    int d1 = 16 + lg * 4 + r;
    O[base + (size_t)(d1 * 4 + h) * N + q0 + lr] = oacc1[r] * invL;
  }
}

// ---------------------------------------------------------------- BN stats (single pass)
__global__ __launch_bounds__(256) void k_bnstat(const float* __restrict__ h,
                                                float* __restrict__ stat) {
  int c = blockIdx.x, s = blockIdx.y, t = threadIdx.x;
  __shared__ float red[256], red2[256];
  const float* base = h + ((size_t)s * B * 256 + c) * N;
  float sum = 0, sq = 0;
  for (int b = 0; b < B; ++b)
    for (int i = t; i < N; i += 256) {
      float v = base[(size_t)b * 256 * N + i];
      sum += v; sq = fmaf(v, v, sq);
    }
  red[t] = sum; red2[t] = sq; __syncthreads();
  for (int sft = 128; sft > 0; sft >>= 1) {
    if (t < sft) { red[t] += red[t + sft]; red2[t] += red2[t + sft]; }
    __syncthreads();
  }
  if (t == 0) {
    float mean = red[0] / (float)(B * N);
    float var = fmaxf(red2[0] / (float)(B * N) - mean * mean, 0.f);
    stat[(s * 256 + c) * 2 + 0] = mean;
    stat[(s * 256 + c) * 2 + 1] = 1.f / sqrtf(var + 1e-5f);
  }
}

// ---------------------------------------------------------------- pairwise dist (8-m tile)
__global__ __launch_bounds__(256) void k_dist(const float* __restrict__ d0,
                                              const float* __restrict__ d1,
                                              float* __restrict__ la) {
  __shared__ float xm[8][128];
  __shared__ float n0s[8];
  int m0 = blockIdx.x * 8, b = blockIdx.y, t = threadIdx.x;
  const float* p0 = d0 + (size_t)b * D * N;
  const float* p1 = d1 + (size_t)b * D * N;
  for (int i = t; i < 8 * 128; i += 256) {
    int mm = i >> 7, d = i & 127;
    xm[mm][d] = p0[(size_t)d * N + m0 + mm];
  }
  __syncthreads();
  if (t < 8) {
    float s = 0;
    for (int d = 0; d < 128; ++d) s += xm[t][d] * xm[t][d];
    n0s[t] = s;
  }
  __syncthreads();
  float dot[8][4] = {{0}};
  float n1[4] = {0, 0, 0, 0};
  for (int d = 0; d < 128; ++d) {
    float v[4];
#pragma unroll
    for (int u = 0; u < 4; ++u) {
      v[u] = p1[(size_t)d * N + t + u * 256];
      n1[u] = fmaf(v[u], v[u], n1[u]);
    }
#pragma unroll
    for (int mm = 0; mm < 8; ++mm) {
      float x = xm[mm][d];
#pragma unroll
      for (int u = 0; u < 4; ++u) dot[mm][u] = fmaf(x, v[u], dot[mm][u]);
    }
  }
  for (int mm = 0; mm < 8; ++mm) {
    float* row = la + ((size_t)b * N + m0 + mm) * N;
#pragma unroll
    for (int u = 0; u < 4; ++u) {
      float dist2 = fmaxf(n0s[mm] + n1[u] - 2.f * dot[mm][u], 1e-30f);
      row[t + u * 256] = -sqrtf(dist2);
    }
  }
}

// ---------------------------------------------------------------- sinkhorn offset form (R17, validated)
__global__ __launch_bounds__(256) void k_row_r(const float* __restrict__ l0,
                                               const float* __restrict__ cvec,
                                               float* __restrict__ r,
                                               int useC) {
  __shared__ float red[256];
  int t = threadIdx.x;
  int bm = blockIdx.x;              // over B*N
  int b = bm >> 10;
  const float* row = l0 + (size_t)bm * N;
  float v0 = row[t], v1 = row[t + 256], v2 = row[t + 512], v3 = row[t + 768];
  if (useC) {
    const float* cl = cvec + (size_t)b * N;
    v0 -= cl[t]; v1 -= cl[t + 256]; v2 -= cl[t + 512]; v3 -= cl[t + 768];
  }
  float mx = fmaxf(fmaxf(v0, v1), fmaxf(v2, v3));
  red[t] = mx; __syncthreads();
  for (int s = 128; s > 0; s >>= 1) {
    if (t < s) red[t] = fmaxf(red[t], red[t + s]);
    __syncthreads();
  }
  mx = red[0]; __syncthreads();
  float se = __expf(v0 - mx) + __expf(v1 - mx) + __expf(v2 - mx) + __expf(v3 - mx);
  red[t] = se; __syncthreads();
  for (int s = 128; s > 0; s >>= 1) {
    if (t < s) red[t] += red[t + s];
    __syncthreads();
  }
  if (t == 0) r[bm] = mx + __logf(red[0]);
}

__global__ __launch_bounds__(256) void k_col_part(const float* __restrict__ l0,
                                                  const float* __restrict__ r,
                                                  float* __restrict__ pmax,
                                                  float* __restrict__ psum) {
  int t = threadIdx.x;
  int n = blockIdx.x * 256 + t;
  int p = blockIdx.y, b = blockIdx.z;
  const float* base = l0 + ((size_t)b * N + p * 32) * N + n;
  const float* rr = r + (size_t)b * N + p * 32;
  float mx = -1e30f, s = 0;
  for (int m = 0; m < 32; ++m) {
    float v = base[(size_t)m * N] - rr[m];
    if (v > mx) { s = s * __expf(mx - v) + 1.f; mx = v; }
    else s += __expf(v - mx);
  }
  pmax[((size_t)b * 32 + p) * N + n] = mx;
  psum[((size_t)b * 32 + p) * N + n] = s;
}

__global__ __launch_bounds__(256) void k_col_fin(const float* __restrict__ pmax,
                                                 const float* __restrict__ psum,
                                                 float* __restrict__ cvec) {
  int i = blockIdx.x * 256 + threadIdx.x;  // over B*N
  int b = i / N, n = i % N;
  float mx = -1e30f;
#pragma unroll
  for (int p = 0; p < 32; ++p) mx = fmaxf(mx, pmax[((size_t)b * 32 + p) * N + n]);
  float s = 0;
#pragma unroll
  for (int p = 0; p < 32; ++p)
    s += psum[((size_t)b * 32 + p) * N + n] * __expf(pmax[((size_t)b * 32 + p) * N + n] - mx);
  cvec[i] = mx + __logf(s);
}

// ---------------------------------------------------------------- rodrigues + transform
__global__ __launch_bounds__(256) void k_rod(const float* __restrict__ pose,
                                             const float* __restrict__ p3d,
                                             float* __restrict__ p3dt) {
  int b = blockIdx.y;
  int n = blockIdx.x * 256 + threadIdx.x;
  const float* aa = pose + b * 6;
  float ax = aa[0], ay = aa[1], az = aa[2];
  float th = fmaxf(sqrtf(ax * ax + ay * ay + az * az), 1e-8f);
  float rx = ax / th, ry = ay / th, rz = az / th;
  float c = cosf(th), s = sinf(th), oc = 1.f - c;
  float R00 = c + oc * rx * rx,      R01 = oc * rx * ry - s * rz, R02 = oc * rx * rz + s * ry;
  float R10 = oc * ry * rx + s * rz, R11 = c + oc * ry * ry,      R12 = oc * ry * rz - s * rx;
  float R20 = oc * rz * rx - s * ry, R21 = oc * rz * ry + s * rx, R22 = c + oc * rz * rz;
  const float* p = p3d + ((size_t)b * N + n) * 3;
  float x = p[0], y = p[1], z = p[2];
  float X = R00 * x + R01 * y + R02 * z + aa[3];
  float Y = R10 * x + R11 * y + R12 * z + aa[4];
  float Z = R20 * x + R21 * y + R22 * z + aa[5];
  float inr = 1.f / sqrtf(X * X + Y * Y + Z * Z);
  float* o = p3dt + ((size_t)b * N + n) * 3;
  o[0] = X * inr; o[1] = Y * inr; o[2] = Z * inr;
}

// ---------------------------------------------------------------- final error (applies r,c offsets)
__global__ __launch_bounds__(256) void k_err(const float* __restrict__ l0,
                                             const float* __restrict__ r,
                                             const float* __restrict__ cvec,
                                             const float* __restrict__ f2,
                                             const float* __restrict__ p3dt,
                                             float* __restrict__ rowsum) {
  __shared__ float red[256];
  int m = blockIdx.x, b = blockIdx.y, t = threadIdx.x;
  const float* row = l0 + ((size_t)b * N + m) * N;
  const float* cl = cvec + (size_t)b * N;
  const float rm = r[(size_t)b * N + m];
  const float* f = f2 + ((size_t)b * N + m) * 3;
  float fx = f[0], fy = f[1], fz = f[2];
  float s = 0;
  for (int n = t; n < N; n += 256) {
    const float* pp = p3dt + ((size_t)b * N + n) * 3;
    float dot = fx * pp[0] + fy * pp[1] + fz * pp[2];
    s += __expf(row[n] - rm - cl[n]) * (1.f - dot);
  }
  red[t] = s; __syncthreads();
  for (int sft = 128; sft > 0; sft >>= 1) {
    if (t < sft) red[t] += red[t + sft];
    __syncthreads();
  }
  if (t == 0) rowsum[(size_t)b * N + m] = red[0];
}

__global__ __launch_bounds__(256) void k_err_fin(const float* __restrict__ rowsum,
                                                 float* __restrict__ out) {
  __shared__ float red[256];
  int b = blockIdx.x, t = threadIdx.x;
  float s = 0;
  for (int i = t; i < N; i += 256) s += rowsum[(size_t)b * N + i];
  red[t] = s; __syncthreads();
  for (int sft = 128; sft > 0; sft >>= 1) {
    if (t < sft) red[t] += red[t + sft];
    __syncthreads();
  }
  if (t == 0) out[b] = red[0];
}

// ================================================================= host
extern "C" void kernel_launch(void* const* d_in, const int* in_sizes, int n_in,
                              void* d_out, int out_size, void* d_ws, size_t ws_size,
                              hipStream_t stream) {
  const float* p2d     = (const float*)d_in[0];
  const float* p3d     = (const float*)d_in[1];
  const float* pose    = (const float*)d_in[2];
  const float* enc2d_w = (const float*)d_in[3];
  const float* enc2d_b = (const float*)d_in[4];
  const float* enc3d_w = (const float*)d_in[5];
  const float* enc3d_b = (const float*)d_in[6];
  const float* proj_w  = (const float*)d_in[7];
  const float* proj_b  = (const float*)d_in[8];
  const float* merge_w = (const float*)d_in[9];
  const float* merge_b = (const float*)d_in[10];
  const float* mlp1_w  = (const float*)d_in[11];
  const float* mlp1_b  = (const float*)d_in[12];
  const float* bn_g    = (const float*)d_in[13];
  const float* bn_b    = (const float*)d_in[14];
  const float* mlp2_w  = (const float*)d_in[15];
  const float* mlp2_b  = (const float*)d_in[16];

  float* W = (float*)d_ws;
  size_t off = 0;
  auto alloc = [&](size_t nelem) { float* p = W + off; off += nelem; return p; };
  const size_t SET = (size_t)B * D * N;
  float* f2    = alloc((size_t)B * N * 3);
  float* p3dt  = alloc((size_t)B * N * 3);
  float* descA = alloc(2 * SET);
  float* descB = alloc(2 * SET);
  float* qkv   = alloc(3 * 2 * SET);
  float* attnb = alloc(2 * SET);
  float* hb    = alloc((size_t)2 * B * 256 * N);
  float* stat  = alloc(2 * 256 * 2);
  float* la    = alloc((size_t)B * N * N);
  float* pmax  = alloc((size_t)B * 32 * N);
  float* psum  = alloc((size_t)B * 32 * N);
  float* cvec  = alloc((size_t)B * N);
  float* rvec  = alloc((size_t)B * N);
  float* rowsum= alloc((size_t)B * N);
  float* wcomb = alloc((size_t)6 * 256 * 256);
  float* bcomb = alloc((size_t)6 * 256);
  (void)ws_size; (void)in_sizes; (void)n_in; (void)out_size;

  float* Qb = qkv;
  float* Kb = qkv + 2 * SET;
  float* Vb = qkv + 4 * SET;
  const size_t DS = (size_t)D * N;

  // precompute merge-folded mlp1 weights (linear identity; removes merge GEMM)
  k_fold<<<dim3(256, 6), 128, 0, stream>>>(mlp1_w, mlp1_b, merge_w, merge_b,
                                           wcomb, bcomb);

  k_norm2d<<<(B * N) / 256, 256, 0, stream>>>(p2d, f2);
  k_encode<<<dim3(N / 4, B), 256, 0, stream>>>(f2, enc2d_w, enc2d_b, descA);
  k_encode<<<dim3(N / 4, B), 256, 0, stream>>>(p3d, enc3d_w, enc3d_b, descA + SET);

  float* dc = descA;
  float* dn = descB;
  for (int i = 0; i < 6; ++i) {
    int cross = (i & 1);
    const float* pw = proj_w + (size_t)i * 3 * D * D;
    const float* pb = proj_b + (size_t)i * 3 * D;
    float* d0 = dc;
    float* d1 = dc + SET;
    const float* sA = cross ? d1 : d0;
    const float* sB = cross ? d0 : d1;

    k_gemm<<<dim3(64, 6), 256, 0, stream>>>(
        d0, d1, sA, sB, pw, pb, nullptr, qkv, nullptr, nullptr, nullptr,
        D, D, DS, DS, D, 2 * SET, 1);
    k_attn<<<dim3(N / 128, NH, 2 * B), 512, 0, stream>>>(Qb, Kb, Vb, attnb);
    // mlp1 with merge folded in: cat part reads attn output directly
    k_gemm<<<dim3(64, 4), 256, 0, stream>>>(
        dc, dc + SET, attnb, attnb + SET, wcomb + (size_t)i * 256 * 256,
        bcomb + (size_t)i * 256, nullptr, hb, nullptr, nullptr, nullptr,
        256, 128, DS, DS, 256, 0, 0);
    k_bnstat<<<dim3(256, 2), 256, 0, stream>>>(hb, stat);
    k_gemm<<<dim3(64, 2), 256, 0, stream>>>(
        hb, hb + (size_t)B * 256 * N, nullptr, nullptr,
        mlp2_w + (size_t)i * D * 256, mlp2_b + (size_t)i * D, dc, dn,
        stat, bn_g + (size_t)i * 256, bn_b + (size_t)i * 256,
        256, 256, (size_t)256 * N, 0, D, 0, 0);
    float* tmp = dc; dc = dn; dn = tmp;
  }

  k_dist<<<dim3(N / 8, B), 256, 0, stream>>>(dc, dc + SET, la);
  for (int it = 0; it < 10; ++it) {
    k_row_r<<<B * N, 256, 0, stream>>>(la, cvec, rvec, it > 0 ? 1 : 0);
    k_col_part<<<dim3(N / 256, 32, B), 256, 0, stream>>>(la, rvec, pmax, psum);
    k_col_fin<<<(B * N) / 256, 256, 0, stream>>>(pmax, psum, cvec);
  }
  k_rod<<<dim3(N / 256, B), 256, 0, stream>>>(pose, p3d, p3dt);
  k_err<<<dim3(N, B), 256, 0, stream>>>(la, rvec, cvec, f2, p3dt, rowsum);
  k_err_fin<<<B, 256, 0, stream>>>(rowsum, (float*)d_out);
}

// Round 22
// 807.329 us; speedup vs baseline: 1.0237x; 1.0237x over previous
//
#include <hip/hip_runtime.h>
#include <hip/hip_bf16.h>

constexpr int B   = 4;
constexpr int N   = 1024;
constexpr int D   = 128;
constexpr int KNN = 10;
constexpr int NH  = 4;

typedef _Float16 half2v __attribute__((ext_vector_type(2)));
typedef _Float16 f16x4  __attribute__((ext_vector_type(4)));
typedef _Float16 f16x8  __attribute__((ext_vector_type(8)));
typedef float    f32x4  __attribute__((ext_vector_type(4)));

static __device__ __forceinline__ half2v pkrtz(float a, float b) {
  return __builtin_bit_cast(half2v, __builtin_amdgcn_cvt_pkrtz(a, b));
}
static __device__ __forceinline__ float h2f(half2v h) {
  return __builtin_bit_cast(float, h);
}

// ---------------------------------------------------------------- norm p2d
__global__ __launch_bounds__(256) void k_norm2d(const float* __restrict__ p2d,
                                                float* __restrict__ f2) {
  int i = blockIdx.x * 256 + threadIdx.x;  // over B*N
  const float* p = p2d + (size_t)i * 3;
  float x = p[0], y = p[1], z = p[2];
  float inr = 1.f / sqrtf(x * x + y * y + z * z);
  float* o = f2 + (size_t)i * 3;
  o[0] = x * inr; o[1] = y * inr; o[2] = z * inr;
}

// ---------------------------------------------------------------- merge-fold precompute (R20, validated)
__global__ __launch_bounds__(128) void k_fold(const float* __restrict__ mlp1_w,
                                              const float* __restrict__ mlp1_b,
                                              const float* __restrict__ merge_w,
                                              const float* __restrict__ merge_b,
                                              float* __restrict__ wcomb,
                                              float* __restrict__ bcomb) {
  __shared__ float red[128];
  const int o = blockIdx.x;        // 0..255
  const int i = blockIdx.y;        // layer 0..5
  const int c = threadIdx.x;       // 0..127
  const float* W1 = mlp1_w + (size_t)i * 256 * 256 + (size_t)o * 256;
  const float* Wm = merge_w + (size_t)i * 128 * 128;
  float* out = wcomb + (size_t)i * 256 * 256 + (size_t)o * 256;
  out[c] = W1[c];
  float acc = 0.f;
#pragma unroll 8
  for (int k = 0; k < 128; ++k)
    acc = fmaf(W1[128 + k], Wm[(size_t)k * 128 + c], acc);
  out[128 + c] = acc;
  red[c] = W1[128 + c] * merge_b[i * 128 + c];
  __syncthreads();
  for (int s = 64; s > 0; s >>= 1) {
    if (c < s) red[c] += red[c + s];
    __syncthreads();
  }
  if (c == 0) bcomb[i * 256 + o] = mlp1_b[i * 256 + o] + red[0];
}

// ---------------------------------------------------------------- KNN encode v2: wave-per-query (R17, validated)
__global__ __launch_bounds__(256) void k_encode(const float* __restrict__ pts,
                                                const float* __restrict__ w,
                                                const float* __restrict__ bias,
                                                float* __restrict__ desc) {
  __shared__ float Px[N], Py[N], Pz[N], Xx[N];
  const int t = threadIdx.x;
  const int l = t & 63, wv = t >> 6;
  const int n = blockIdx.x * 4 + wv;
  const int b = blockIdx.y;
  const float* pb = pts + (size_t)b * N * 3;
  for (int i = t; i < N; i += 256) {
    float x = pb[i * 3 + 0], y = pb[i * 3 + 1], z = pb[i * 3 + 2];
    Px[i] = x; Py[i] = y; Pz[i] = z;
    Xx[i] = x * x + y * y + z * z;
  }
  __syncthreads();
  const float cx = Px[n], cy = Py[n], cz = Pz[n], cxx = Xx[n];
  float dist[16];
#pragma unroll
  for (int i = 0; i < 16; ++i) {
    int j = i * 64 + l;
    float ip = cx * Px[j] + cy * Py[j] + cz * Pz[j];
    dist[i] = 2.f * ip - cxx - Xx[j];
  }
  float sx = 0.f, sy = 0.f, sz = 0.f;
#pragma unroll
  for (int kk = 0; kk < KNN; ++kk) {
    float bv = dist[0]; int bi = l;
#pragma unroll
    for (int i = 1; i < 16; ++i) {
      if (dist[i] > bv) { bv = dist[i]; bi = i * 64 + l; }
    }
#pragma unroll
    for (int sft = 1; sft < 64; sft <<= 1) {
      float v2 = __shfl_xor(bv, sft, 64);
      int   i2 = __shfl_xor(bi, sft, 64);
      if (v2 > bv || (v2 == bv && i2 < bi)) { bv = v2; bi = i2; }
    }
    sx += Px[bi]; sy += Py[bi]; sz += Pz[bi];
    if ((bi & 63) == l) {
      int io = bi >> 6;
#pragma unroll
      for (int i = 0; i < 16; ++i)
        if (i == io) dist[i] = -3.0e38f;
    }
  }
  const float invk = 1.f / KNN;
  float feat[6];
  feat[0] = sx * invk - cx; feat[1] = sy * invk - cy; feat[2] = sz * invk - cz;
  feat[3] = cx; feat[4] = cy; feat[5] = cz;
#pragma unroll
  for (int rep = 0; rep < 2; ++rep) {
    int c = rep * 64 + l;
    const float* wr = w + c * 6;
    float a = bias[c];
#pragma unroll
    for (int j = 0; j < 6; ++j) a += wr[j] * feat[j];
    desc[((size_t)b * D + c) * N + n] = a;
  }
}

// ---------------------------------------------------------------- tiled GEMM conv v3: MFMA f16 (R15, validated)
__global__ __launch_bounds__(256) void k_gemm(
    const float* __restrict__ pA0, const float* __restrict__ pA1,
    const float* __restrict__ pB0, const float* __restrict__ pB1,
    const float* __restrict__ w, const float* __restrict__ bias,
    const float* __restrict__ res, float* __restrict__ out,
    const float* __restrict__ stat, const float* __restrict__ g,
    const float* __restrict__ bt,
    int Cin, int catOff, size_t a_bstr, size_t b_bstr,
    int segCout, size_t segStride, int qkvMode) {
  __shared__ _Float16 As[64][48];
  __shared__ half2v   Bs[16][132];
  __shared__ float Ac[256], Bc[256];
  const int tid = threadIdx.x;
  const int wv  = tid >> 6;
  const int l   = tid & 63;
  const int wo  = wv >> 1;
  const int wn  = wv & 1;
  const int lr  = l & 15;
  const int lg  = l >> 4;
  const int o0 = blockIdx.y * 64;
  const int zb = blockIdx.x;
  const int z  = zb >> 3;
  const int n0 = (zb & 7) * 128;
  const int s = z >> 2, b = z & 3;
  const int seg = o0 / segCout;
  const int oo  = o0 % segCout;

  const float* XA = (s ? pA1 : pA0) + (size_t)b * a_bstr;
  const float* XB = pB0 ? ((s ? pB1 : pB0) + (size_t)b * b_bstr) : nullptr;
  const bool segB = qkvMode && (seg > 0);

  if (stat) {
    const float* st = stat + (size_t)s * 256 * 2;
    float A = st[tid * 2 + 1] * g[tid];
    Ac[tid] = A;
    Bc[tid] = fmaf(-st[tid * 2 + 0], A, bt[tid]);
  }

  f32x4 acc[2][4];
#pragma unroll
  for (int i = 0; i < 2; ++i)
#pragma unroll
    for (int j = 0; j < 4; ++j) acc[i][j] = (f32x4){0.f, 0.f, 0.f, 0.f};

  for (int kb = 0; kb < Cin; kb += 32) {
    __syncthreads();
#pragma unroll
    for (int j = 0; j < 2; ++j) {
      int idx = j * 256 + tid;
      int o = idx >> 3, c4 = (idx & 7) * 4;
      float4 wvv = *(const float4*)&w[(size_t)(o0 + o) * Cin + kb + c4];
      *(half2v*)&As[o][c4]     = pkrtz(wvv.x, wvv.y);
      *(half2v*)&As[o][c4 + 2] = pkrtz(wvv.z, wvv.w);
    }
#pragma unroll
    for (int j = 0; j < 2; ++j) {
      int idx = j * 256 + tid;
      int rp = idx >> 5, c4 = (idx & 31) * 4;
      int c0 = kb + 2 * rp, c1 = c0 + 1;
      const float* s0; int cc0 = c0;
      const float* s1; int cc1 = c1;
      if (qkvMode) {
        s0 = segB ? XB : XA; s1 = s0;
      } else {
        if (c0 >= catOff) { s0 = XB; cc0 = c0 - catOff; } else s0 = XA;
        if (c1 >= catOff) { s1 = XB; cc1 = c1 - catOff; } else s1 = XA;
      }
      float4 v0 = *(const float4*)&s0[(size_t)cc0 * N + n0 + c4];
      float4 v1 = *(const float4*)&s1[(size_t)cc1 * N + n0 + c4];
      if (stat) {
        float A0 = Ac[c0], B0 = Bc[c0], A1 = Ac[c1], B1 = Bc[c1];
        v0.x = fmaxf(fmaf(v0.x, A0, B0), 0.f);
        v0.y = fmaxf(fmaf(v0.y, A0, B0), 0.f);
        v0.z = fmaxf(fmaf(v0.z, A0, B0), 0.f);
        v0.w = fmaxf(fmaf(v0.w, A0, B0), 0.f);
        v1.x = fmaxf(fmaf(v1.x, A1, B1), 0.f);
        v1.y = fmaxf(fmaf(v1.y, A1, B1), 0.f);
        v1.z = fmaxf(fmaf(v1.z, A1, B1), 0.f);
        v1.w = fmaxf(fmaf(v1.w, A1, B1), 0.f);
      }
      float4 packed;
      packed.x = h2f(pkrtz(v0.x, v1.x));
      packed.y = h2f(pkrtz(v0.y, v1.y));
      packed.z = h2f(pkrtz(v0.z, v1.z));
      packed.w = h2f(pkrtz(v0.w, v1.w));
      *(float4*)&Bs[rp][c4] = packed;
    }
    __syncthreads();
    f16x8 afr0 = *(const f16x8*)&As[wo * 32 + lr][lg * 8];
    f16x8 afr1 = *(const f16x8*)&As[wo * 32 + 16 + lr][lg * 8];
#pragma unroll
    for (int tj = 0; tj < 4; ++tj) {
      int nn = wn * 64 + tj * 16 + lr;
      float4 btmp;
      btmp.x = *(const float*)&Bs[lg * 4 + 0][nn];
      btmp.y = *(const float*)&Bs[lg * 4 + 1][nn];
      btmp.z = *(const float*)&Bs[lg * 4 + 2][nn];
      btmp.w = *(const float*)&Bs[lg * 4 + 3][nn];
      f16x8 bfr = __builtin_bit_cast(f16x8, btmp);
      acc[0][tj] = __builtin_amdgcn_mfma_f32_16x16x32_f16(afr0, bfr, acc[0][tj], 0, 0, 0);
      acc[1][tj] = __builtin_amdgcn_mfma_f32_16x16x32_f16(afr1, bfr, acc[1][tj], 0, 0, 0);
    }
  }
#pragma unroll
  for (int ti = 0; ti < 2; ++ti) {
#pragma unroll
    for (int tj = 0; tj < 4; ++tj) {
      int nn = n0 + wn * 64 + tj * 16 + lr;
#pragma unroll
      for (int r = 0; r < 4; ++r) {
        int lrow = wo * 32 + ti * 16 + lg * 4 + r;
        size_t ob = (size_t)seg * segStride +
                    ((size_t)z * segCout + oo + lrow) * N + nn;
        float v = acc[ti][tj][r] + bias[o0 + lrow];
        if (res) v += res[ob];
        out[ob] = v;
      }
    }
  }
}

// ---------------------------------------------------------------- attention v10: MFMA flash (R16, validated)
__global__ __launch_bounds__(512) void k_attn(const float* __restrict__ Q,
                                              const float* __restrict__ Kt,
                                              const float* __restrict__ Vt,
                                              float* __restrict__ O) {
  __shared__ _Float16 Klds[128][40];
  __shared__ _Float16 Vlds[32][136];
  const int t  = threadIdx.x;
  const int l  = t & 63, w = t >> 6;
  const int lr = l & 15, lg = l >> 4;
  const int q0 = blockIdx.x * 128 + w * 16;
  const int h  = blockIdx.y;
  const int z  = blockIdx.z;
  const size_t base = (size_t)z * (size_t)(D * N);
  const float* Kg = Kt + base + (size_t)h * N;
  const float* Vg = Vt + base + (size_t)h * N;
  const float scale = 0.17677669529663687f;

  f16x8 qfrag;
  {
    float qv[8];
#pragma unroll
    for (int j = 0; j < 8; ++j)
      qv[j] = Q[base + (size_t)((lg * 8 + j) * 4 + h) * N + q0 + lr] * scale;
    float4 qp;
    qp.x = h2f(pkrtz(qv[0], qv[1]));
    qp.y = h2f(pkrtz(qv[2], qv[3]));
    qp.z = h2f(pkrtz(qv[4], qv[5]));
    qp.w = h2f(pkrtz(qv[6], qv[7]));
    qfrag = __builtin_bit_cast(f16x8, qp);
  }

  f32x4 oacc0 = (f32x4){0.f, 0.f, 0.f, 0.f};
  f32x4 oacc1 = (f32x4){0.f, 0.f, 0.f, 0.f};
  float m = -1e30f, lsum = 0.f;

  for (int c = 0; c < 8; ++c) {
    const int k0 = c * 128;
    __syncthreads();
    {
      int kk = t & 127, d0 = (t >> 7) * 8;
      float kv[8];
#pragma unroll
      for (int j = 0; j < 8; ++j)
        kv[j] = Kg[(size_t)((d0 + j) * 4) * N + k0 + kk];
      float4 pk;
      pk.x = h2f(pkrtz(kv[0], kv[1]));
      pk.y = h2f(pkrtz(kv[2], kv[3]));
      pk.z = h2f(pkrtz(kv[4], kv[5]));
      pk.w = h2f(pkrtz(kv[6], kv[7]));
      *(float4*)&Klds[kk][d0] = pk;
      int dv = t & 31, ko = (t >> 5) * 8;
      const float* vp = Vg + (size_t)(dv * 4) * N + k0 + ko;
      float4 v0 = *(const float4*)vp;
      float4 v1 = *(const float4*)(vp + 4);
      float4 pv;
      pv.x = h2f(pkrtz(v0.x, v0.y)); pv.y = h2f(pkrtz(v0.z, v0.w));
      pv.z = h2f(pkrtz(v1.x, v1.y)); pv.w = h2f(pkrtz(v1.z, v1.w));
      *(float4*)&Vlds[dv][ko] = pv;
    }
    __syncthreads();
#pragma unroll
    for (int kt = 0; kt < 8; ++kt) {
      f16x8 kfrag = *(const f16x8*)&Klds[kt * 16 + lr][lg * 8];
      f32x4 s = __builtin_amdgcn_mfma_f32_16x16x32_f16(
          kfrag, qfrag, (f32x4){0.f, 0.f, 0.f, 0.f}, 0, 0, 0);
      float tmax = fmaxf(fmaxf(s[0], s[1]), fmaxf(s[2], s[3]));
      tmax = fmaxf(tmax, __shfl_xor(tmax, 16, 64));
      tmax = fmaxf(tmax, __shfl_xor(tmax, 32, 64));
      float nm = fmaxf(m, tmax);
      float corr = __expf(m - nm);
      m = nm;
      lsum *= corr;
#pragma unroll
      for (int r = 0; r < 4; ++r) { oacc0[r] *= corr; oacc1[r] *= corr; }
      float p0 = __expf(s[0] - m), p1 = __expf(s[1] - m);
      float p2 = __expf(s[2] - m), p3 = __expf(s[3] - m);
      float ts = p0 + p1 + p2 + p3;
      ts += __shfl_xor(ts, 16, 64);
      ts += __shfl_xor(ts, 32, 64);
      lsum += ts;
      float2 ptmp;
      ptmp.x = h2f(pkrtz(p0, p1));
      ptmp.y = h2f(pkrtz(p2, p3));
      f16x4 pfrag = __builtin_bit_cast(f16x4, ptmp);
      float2 vt0 = *(const float2*)&Vlds[lr][kt * 16 + lg * 4];
      float2 vt1 = *(const float2*)&Vlds[16 + lr][kt * 16 + lg * 4];
      f16x4 vf0 = __builtin_bit_cast(f16x4, vt0);
      f16x4 vf1 = __builtin_bit_cast(f16x4, vt1);
      oacc0 = __builtin_amdgcn_mfma_f32_16x16x16f16(vf0, pfrag, oacc0, 0, 0, 0);
      oacc1 = __builtin_amdgcn_mfma_f32_16x16x16f16(vf1, pfrag, oacc1, 0, 0, 0);
    }
  }
  float invL = 1.f / lsum;
#pragma unroll
  for (int r = 0; r < 4; ++r) {
    int d0 = lg * 4 + r;
    O[base + (size_t)(d0 * 4 + h) * N + q0 + lr] = oacc0[r] * invL;
    int d1 = 16 + lg * 4 + r;
    O[base + (size_t)(d1 * 4 + h) * N + q0 + lr] = oacc1[r] * invL;
  }
}

// ---------------------------------------------------------------- BN stats (single pass)
__global__ __launch_bounds__(256) void k_bnstat(const float* __restrict__ h,
                                                float* __restrict__ stat) {
  int c = blockIdx.x, s = blockIdx.y, t = threadIdx.x;
  __shared__ float red[256], red2[256];
  const float* base = h + ((size_t)s * B * 256 + c) * N;
  float sum = 0, sq = 0;
  for (int b = 0; b < B; ++b)
    for (int i = t; i < N; i += 256) {
      float v = base[(size_t)b * 256 * N + i];
      sum += v; sq = fmaf(v, v, sq);
    }
  red[t] = sum; red2[t] = sq; __syncthreads();
  for (int sft = 128; sft > 0; sft >>= 1) {
    if (t < sft) { red[t] += red[t + sft]; red2[t] += red2[t + sft]; }
    __syncthreads();
  }
  if (t == 0) {
    float mean = red[0] / (float)(B * N);
    float var = fmaxf(red2[0] / (float)(B * N) - mean * mean, 0.f);
    stat[(s * 256 + c) * 2 + 0] = mean;
    stat[(s * 256 + c) * 2 + 1] = 1.f / sqrtf(var + 1e-5f);
  }
}

// ---------------------------------------------------------------- pairwise dist (8-m tile)
__global__ __launch_bounds__(256) void k_dist(const float* __restrict__ d0,
                                              const float* __restrict__ d1,
                                              float* __restrict__ la) {
  __shared__ float xm[8][128];
  __shared__ float n0s[8];
  int m0 = blockIdx.x * 8, b = blockIdx.y, t = threadIdx.x;
  const float* p0 = d0 + (size_t)b * D * N;
  const float* p1 = d1 + (size_t)b * D * N;
  for (int i = t; i < 8 * 128; i += 256) {
    int mm = i >> 7, d = i & 127;
    xm[mm][d] = p0[(size_t)d * N + m0 + mm];
  }
  __syncthreads();
  if (t < 8) {
    float s = 0;
    for (int d = 0; d < 128; ++d) s += xm[t][d] * xm[t][d];
    n0s[t] = s;
  }
  __syncthreads();
  float dot[8][4] = {{0}};
  float n1[4] = {0, 0, 0, 0};
  for (int d = 0; d < 128; ++d) {
    float v[4];
#pragma unroll
    for (int u = 0; u < 4; ++u) {
      v[u] = p1[(size_t)d * N + t + u * 256];
      n1[u] = fmaf(v[u], v[u], n1[u]);
    }
#pragma unroll
    for (int mm = 0; mm < 8; ++mm) {
      float x = xm[mm][d];
#pragma unroll
      for (int u = 0; u < 4; ++u) dot[mm][u] = fmaf(x, v[u], dot[mm][u]);
    }
  }
  for (int mm = 0; mm < 8; ++mm) {
    float* row = la + ((size_t)b * N + m0 + mm) * N;
#pragma unroll
    for (int u = 0; u < 4; ++u) {
      float dist2 = fmaxf(n0s[mm] + n1[u] - 2.f * dot[mm][u], 1e-30f);
      row[t + u * 256] = -sqrtf(dist2);
    }
  }
}

// ---------------------------------------------------------------- sinkhorn row v2: wave-per-row
// grid (B*N/4, ), 256 thr = 4 waves; wave owns one row. Lane reads 4 coalesced
// float4 (16 vals), online LSE locally, 6-level shfl_xor LSE-merge. ZERO
// barriers / LDS (old: ~16 syncthreads over two tree reductions).
__global__ __launch_bounds__(256) void k_row_r(const float* __restrict__ l0,
                                               const float* __restrict__ cvec,
                                               float* __restrict__ r,
                                               int useC) {
  const int t = threadIdx.x;
  const int l = t & 63, wv = t >> 6;
  const int bm = blockIdx.x * 4 + wv;   // over B*N
  const int b = bm >> 10;
  const float* row = l0 + (size_t)bm * N;
  const float* cl = cvec + (size_t)b * N;
  float mx = -1e30f, s = 0.f;
#pragma unroll
  for (int i = 0; i < 4; ++i) {
    int n4 = l * 4 + i * 256;
    float4 v = *(const float4*)&row[n4];
    if (useC) {
      float4 c4 = *(const float4*)&cl[n4];
      v.x -= c4.x; v.y -= c4.y; v.z -= c4.z; v.w -= c4.w;
    }
    float tm = fmaxf(fmaxf(v.x, v.y), fmaxf(v.z, v.w));
    if (tm > mx) { s *= __expf(mx - tm); mx = tm; }
    s += __expf(v.x - mx) + __expf(v.y - mx) + __expf(v.z - mx) + __expf(v.w - mx);
  }
#pragma unroll
  for (int sft = 1; sft < 64; sft <<= 1) {
    float m2 = __shfl_xor(mx, sft, 64);
    float s2 = __shfl_xor(s, sft, 64);
    float nm = fmaxf(mx, m2);
    s = s * __expf(mx - nm) + s2 * __expf(m2 - nm);
    mx = nm;
  }
  if (l == 0) r[bm] = mx + __logf(s);
}

__global__ __launch_bounds__(256) void k_col_part(const float* __restrict__ l0,
                                                  const float* __restrict__ r,
                                                  float* __restrict__ pmax,
                                                  float* __restrict__ psum) {
  int t = threadIdx.x;
  int n = blockIdx.x * 256 + t;
  int p = blockIdx.y, b = blockIdx.z;
  const float* base = l0 + ((size_t)b * N + p * 32) * N + n;
  const float* rr = r + (size_t)b * N + p * 32;
  float mx = -1e30f, s = 0;
  for (int m = 0; m < 32; ++m) {
    float v = base[(size_t)m * N] - rr[m];
    if (v > mx) { s = s * __expf(mx - v) + 1.f; mx = v; }
    else s += __expf(v - mx);
  }
  pmax[((size_t)b * 32 + p) * N + n] = mx;
  psum[((size_t)b * 32 + p) * N + n] = s;
}

// ---------------------------------------------------------------- col finalize v2: 4-way p-split
// grid (16*B, ), 256 thr: tn = n within 64-group, tp = p-quarter (8 partials
// each), LDS combine of the 4 quarters. 4x parallelism + 4x shorter chain.
__global__ __launch_bounds__(256) void k_col_fin(const float* __restrict__ pmax,
                                                 const float* __restrict__ psum,
                                                 float* __restrict__ cvec) {
  __shared__ float smx[4][64], ssm[4][64];
  const int blk = blockIdx.x;            // 0..16*B-1
  const int b = blk >> 4;
  const int n0 = (blk & 15) * 64;
  const int tn = threadIdx.x & 63, tp = threadIdx.x >> 6;
  const int n = n0 + tn;
  float mx = -1e30f, s = 0.f;
#pragma unroll
  for (int pi = 0; pi < 8; ++pi) {
    int p = tp * 8 + pi;
    float m2 = pmax[((size_t)b * 32 + p) * N + n];
    float s2 = psum[((size_t)b * 32 + p) * N + n];
    float nm = fmaxf(mx, m2);
    s = s * __expf(mx - nm) + s2 * __expf(m2 - nm);
    mx = nm;
  }
  smx[tp][tn] = mx; ssm[tp][tn] = s;
  __syncthreads();
  if (tp == 0) {
#pragma unroll
    for (int q = 1; q < 4; ++q) {
      float m2 = smx[q][tn], s2 = ssm[q][tn];
      float nm = fmaxf(mx, m2);
      s = s * __expf(mx - nm) + s2 * __expf(m2 - nm);
      mx = nm;
    }
    cvec[(size_t)b * N + n] = mx + __logf(s);
  }
}

// ---------------------------------------------------------------- rodrigues + transform
__global__ __launch_bounds__(256) void k_rod(const float* __restrict__ pose,
                                             const float* __restrict__ p3d,
                                             float* __restrict__ p3dt) {
  int b = blockIdx.y;
  int n = blockIdx.x * 256 + threadIdx.x;
  const float* aa = pose + b * 6;
  float ax = aa[0], ay = aa[1], az = aa[2];
  float th = fmaxf(sqrtf(ax * ax + ay * ay + az * az), 1e-8f);
  float rx = ax / th, ry = ay / th, rz = az / th;
  float c = cosf(th), s = sinf(th), oc = 1.f - c;
  float R00 = c + oc * rx * rx,      R01 = oc * rx * ry - s * rz, R02 = oc * rx * rz + s * ry;
  float R10 = oc * ry * rx + s * rz, R11 = c + oc * ry * ry,      R12 = oc * ry * rz - s * rx;
  float R20 = oc * rz * rx - s * ry, R21 = oc * rz * ry + s * rx, R22 = c + oc * rz * rz;
  const float* p = p3d + ((size_t)b * N + n) * 3;
  float x = p[0], y = p[1], z = p[2];
  float X = R00 * x + R01 * y + R02 * z + aa[3];
  float Y = R10 * x + R11 * y + R12 * z + aa[4];
  float Z = R20 * x + R21 * y + R22 * z + aa[5];
  float inr = 1.f / sqrtf(X * X + Y * Y + Z * Z);
  float* o = p3dt + ((size_t)b * N + n) * 3;
  o[0] = X * inr; o[1] = Y * inr; o[2] = Z * inr;
}

// ---------------------------------------------------------------- final error (applies r,c offsets)
__global__ __launch_bounds__(256) void k_err(const float* __restrict__ l0,
                                             const float* __restrict__ r,
                                             const float* __restrict__ cvec,
                                             const float* __restrict__ f2,
                                             const float* __restrict__ p3dt,
                                             float* __restrict__ rowsum) {
  __shared__ float red[256];
  int m = blockIdx.x, b = blockIdx.y, t = threadIdx.x;
  const float* row = l0 + ((size_t)b * N + m) * N;
  const float* cl = cvec + (size_t)b * N;
  const float rm = r[(size_t)b * N + m];
  const float* f = f2 + ((size_t)b * N + m) * 3;
  float fx = f[0], fy = f[1], fz = f[2];
  float s = 0;
  for (int n = t; n < N; n += 256) {
    const float* pp = p3dt + ((size_t)b * N + n) * 3;
    float dot = fx * pp[0] + fy * pp[1] + fz * pp[2];
    s += __expf(row[n] - rm - cl[n]) * (1.f - dot);
  }
  red[t] = s; __syncthreads();
  for (int sft = 128; sft > 0; sft >>= 1) {
    if (t < sft) red[t] += red[t + sft];
    __syncthreads();
  }
  if (t == 0) rowsum[(size_t)b * N + m] = red[0];
}

__global__ __launch_bounds__(256) void k_err_fin(const float* __restrict__ rowsum,
                                                 float* __restrict__ out) {
  __shared__ float red[256];
  int b = blockIdx.x, t = threadIdx.x;
  float s = 0;
  for (int i = t; i < N; i += 256) s += rowsum[(size_t)b * N + i];
  red[t] = s; __syncthreads();
  for (int sft = 128; sft > 0; sft >>= 1) {
    if (t < sft) red[t] += red[t + sft];
    __syncthreads();
  }
  if (t == 0) out[b] = red[0];
}

// ================================================================= host
extern "C" void kernel_launch(void* const* d_in, const int* in_sizes, int n_in,
                              void* d_out, int out_size, void* d_ws, size_t ws_size,
                              hipStream_t stream) {
  const float* p2d     = (const float*)d_in[0];
  const float* p3d     = (const float*)d_in[1];
  const float* pose    = (const float*)d_in[2];
  const float* enc2d_w = (const float*)d_in[3];
  const float* enc2d_b = (const float*)d_in[4];
  const float* enc3d_w = (const float*)d_in[5];
  const float* enc3d_b = (const float*)d_in[6];
  const float* proj_w  = (const float*)d_in[7];
  const float* proj_b  = (const float*)d_in[8];
  const float* merge_w = (const float*)d_in[9];
  const float* merge_b = (const float*)d_in[10];
  const float* mlp1_w  = (const float*)d_in[11];
  const float* mlp1_b  = (const float*)d_in[12];
  const float* bn_g    = (const float*)d_in[13];
  const float* bn_b    = (const float*)d_in[14];
  const float* mlp2_w  = (const float*)d_in[15];
  const float* mlp2_b  = (const float*)d_in[16];

  float* W = (float*)d_ws;
  size_t off = 0;
  auto alloc = [&](size_t nelem) { float* p = W + off; off += nelem; return p; };
  const size_t SET = (size_t)B * D * N;
  float* f2    = alloc((size_t)B * N * 3);
  float* p3dt  = alloc((size_t)B * N * 3);
  float* descA = alloc(2 * SET);
  float* descB = alloc(2 * SET);
  float* qkv   = alloc(3 * 2 * SET);
  float* attnb = alloc(2 * SET);
  float* hb    = alloc((size_t)2 * B * 256 * N);
  float* stat  = alloc(2 * 256 * 2);
  float* la    = alloc((size_t)B * N * N);
  float* pmax  = alloc((size_t)B * 32 * N);
  float* psum  = alloc((size_t)B * 32 * N);
  float* cvec  = alloc((size_t)B * N);
  float* rvec  = alloc((size_t)B * N);
  float* rowsum= alloc((size_t)B * N);
  float* wcomb = alloc((size_t)6 * 256 * 256);
  float* bcomb = alloc((size_t)6 * 256);
  (void)ws_size; (void)in_sizes; (void)n_in; (void)out_size;

  float* Qb = qkv;
  float* Kb = qkv + 2 * SET;
  float* Vb = qkv + 4 * SET;
  const size_t DS = (size_t)D * N;

  k_fold<<<dim3(256, 6), 128, 0, stream>>>(mlp1_w, mlp1_b, merge_w, merge_b,
                                           wcomb, bcomb);

  k_norm2d<<<(B * N) / 256, 256, 0, stream>>>(p2d, f2);
  k_encode<<<dim3(N / 4, B), 256, 0, stream>>>(f2, enc2d_w, enc2d_b, descA);
  k_encode<<<dim3(N / 4, B), 256, 0, stream>>>(p3d, enc3d_w, enc3d_b, descA + SET);

  float* dc = descA;
  float* dn = descB;
  for (int i = 0; i < 6; ++i) {
    int cross = (i & 1);
    const float* pw = proj_w + (size_t)i * 3 * D * D;
    const float* pb = proj_b + (size_t)i * 3 * D;
    float* d0 = dc;
    float* d1 = dc + SET;
    const float* sA = cross ? d1 : d0;
    const float* sB = cross ? d0 : d1;

    k_gemm<<<dim3(64, 6), 256, 0, stream>>>(
        d0, d1, sA, sB, pw, pb, nullptr, qkv, nullptr, nullptr, nullptr,
        D, D, DS, DS, D, 2 * SET, 1);
    k_attn<<<dim3(N / 128, NH, 2 * B), 512, 0, stream>>>(Qb, Kb, Vb, attnb);
    k_gemm<<<dim3(64, 4), 256, 0, stream>>>(
        dc, dc + SET, attnb, attnb + SET, wcomb + (size_t)i * 256 * 256,
        bcomb + (size_t)i * 256, nullptr, hb, nullptr, nullptr, nullptr,
        256, 128, DS, DS, 256, 0, 0);
    k_bnstat<<<dim3(256, 2), 256, 0, stream>>>(hb, stat);
    k_gemm<<<dim3(64, 2), 256, 0, stream>>>(
        hb, hb + (size_t)B * 256 * N, nullptr, nullptr,
        mlp2_w + (size_t)i * D * 256, mlp2_b + (size_t)i * D, dc, dn,
        stat, bn_g + (size_t)i * 256, bn_b + (size_t)i * 256,
        256, 256, (size_t)256 * N, 0, D, 0, 0);
    float* tmp = dc; dc = dn; dn = tmp;
  }

  k_dist<<<dim3(N / 8, B), 256, 0, stream>>>(dc, dc + SET, la);
  for (int it = 0; it < 10; ++it) {
    k_row_r<<<(B * N) / 4, 256, 0, stream>>>(la, cvec, rvec, it > 0 ? 1 : 0);
    k_col_part<<<dim3(N / 256, 32, B), 256, 0, stream>>>(la, rvec, pmax, psum);
    k_col_fin<<<16 * B, 256, 0, stream>>>(pmax, psum, cvec);
  }
  k_rod<<<dim3(N / 256, B), 256, 0, stream>>>(pose, p3d, p3dt);
  k_err<<<dim3(N, B), 256, 0, stream>>>(la, rvec, cvec, f2, p3dt, rowsum);
  k_err_fin<<<B, 256, 0, stream>>>(rowsum, (float*)d_out);
}

// Round 23
// 772.716 us; speedup vs baseline: 1.0696x; 1.0448x over previous
//
#include <hip/hip_runtime.h>
#include <hip/hip_bf16.h>

constexpr int B   = 4;
constexpr int N   = 1024;
constexpr int D   = 128;
constexpr int KNN = 10;
constexpr int NH  = 4;

typedef _Float16 half2v __attribute__((ext_vector_type(2)));
typedef _Float16 f16x4  __attribute__((ext_vector_type(4)));
typedef _Float16 f16x8  __attribute__((ext_vector_type(8)));
typedef float    f32x4  __attribute__((ext_vector_type(4)));

static __device__ __forceinline__ half2v pkrtz(float a, float b) {
  return __builtin_bit_cast(half2v, __builtin_amdgcn_cvt_pkrtz(a, b));
}
static __device__ __forceinline__ float h2f(half2v h) {
  return __builtin_bit_cast(float, h);
}

// ---------------------------------------------------------------- norm p2d
__global__ __launch_bounds__(256) void k_norm2d(const float* __restrict__ p2d,
                                                float* __restrict__ f2) {
  int i = blockIdx.x * 256 + threadIdx.x;  // over B*N
  const float* p = p2d + (size_t)i * 3;
  float x = p[0], y = p[1], z = p[2];
  float inr = 1.f / sqrtf(x * x + y * y + z * z);
  float* o = f2 + (size_t)i * 3;
  o[0] = x * inr; o[1] = y * inr; o[2] = z * inr;
}

// ---------------------------------------------------------------- merge-fold precompute (R20, validated)
__global__ __launch_bounds__(128) void k_fold(const float* __restrict__ mlp1_w,
                                              const float* __restrict__ mlp1_b,
                                              const float* __restrict__ merge_w,
                                              const float* __restrict__ merge_b,
                                              float* __restrict__ wcomb,
                                              float* __restrict__ bcomb) {
  __shared__ float red[128];
  const int o = blockIdx.x;        // 0..255
  const int i = blockIdx.y;        // layer 0..5
  const int c = threadIdx.x;       // 0..127
  const float* W1 = mlp1_w + (size_t)i * 256 * 256 + (size_t)o * 256;
  const float* Wm = merge_w + (size_t)i * 128 * 128;
  float* out = wcomb + (size_t)i * 256 * 256 + (size_t)o * 256;
  out[c] = W1[c];
  float acc = 0.f;
#pragma unroll 8
  for (int k = 0; k < 128; ++k)
    acc = fmaf(W1[128 + k], Wm[(size_t)k * 128 + c], acc);
  out[128 + c] = acc;
  red[c] = W1[128 + c] * merge_b[i * 128 + c];
  __syncthreads();
  for (int s = 64; s > 0; s >>= 1) {
    if (c < s) red[c] += red[c + s];
    __syncthreads();
  }
  if (c == 0) bcomb[i * 256 + o] = mlp1_b[i * 256 + o] + red[0];
}

// ---------------------------------------------------------------- KNN encode v2: wave-per-query (R17, validated)
__global__ __launch_bounds__(256) void k_encode(const float* __restrict__ pts,
                                                const float* __restrict__ w,
                                                const float* __restrict__ bias,
                                                float* __restrict__ desc) {
  __shared__ float Px[N], Py[N], Pz[N], Xx[N];
  const int t = threadIdx.x;
  const int l = t & 63, wv = t >> 6;
  const int n = blockIdx.x * 4 + wv;
  const int b = blockIdx.y;
  const float* pb = pts + (size_t)b * N * 3;
  for (int i = t; i < N; i += 256) {
    float x = pb[i * 3 + 0], y = pb[i * 3 + 1], z = pb[i * 3 + 2];
    Px[i] = x; Py[i] = y; Pz[i] = z;
    Xx[i] = x * x + y * y + z * z;
  }
  __syncthreads();
  const float cx = Px[n], cy = Py[n], cz = Pz[n], cxx = Xx[n];
  float dist[16];
#pragma unroll
  for (int i = 0; i < 16; ++i) {
    int j = i * 64 + l;
    float ip = cx * Px[j] + cy * Py[j] + cz * Pz[j];
    dist[i] = 2.f * ip - cxx - Xx[j];
  }
  float sx = 0.f, sy = 0.f, sz = 0.f;
#pragma unroll
  for (int kk = 0; kk < KNN; ++kk) {
    float bv = dist[0]; int bi = l;
#pragma unroll
    for (int i = 1; i < 16; ++i) {
      if (dist[i] > bv) { bv = dist[i]; bi = i * 64 + l; }
    }
#pragma unroll
    for (int sft = 1; sft < 64; sft <<= 1) {
      float v2 = __shfl_xor(bv, sft, 64);
      int   i2 = __shfl_xor(bi, sft, 64);
      if (v2 > bv || (v2 == bv && i2 < bi)) { bv = v2; bi = i2; }
    }
    sx += Px[bi]; sy += Py[bi]; sz += Pz[bi];
    if ((bi & 63) == l) {
      int io = bi >> 6;
#pragma unroll
      for (int i = 0; i < 16; ++i)
        if (i == io) dist[i] = -3.0e38f;
    }
  }
  const float invk = 1.f / KNN;
  float feat[6];
  feat[0] = sx * invk - cx; feat[1] = sy * invk - cy; feat[2] = sz * invk - cz;
  feat[3] = cx; feat[4] = cy; feat[5] = cz;
#pragma unroll
  for (int rep = 0; rep < 2; ++rep) {
    int c = rep * 64 + l;
    const float* wr = w + c * 6;
    float a = bias[c];
#pragma unroll
    for (int j = 0; j < 6; ++j) a += wr[j] * feat[j];
    desc[((size_t)b * D + c) * N + n] = a;
  }
}

// ---------------------------------------------------------------- tiled GEMM conv v3: MFMA f16 (R15, validated)
__global__ __launch_bounds__(256) void k_gemm(
    const float* __restrict__ pA0, const float* __restrict__ pA1,
    const float* __restrict__ pB0, const float* __restrict__ pB1,
    const float* __restrict__ w, const float* __restrict__ bias,
    const float* __restrict__ res, float* __restrict__ out,
    const float* __restrict__ stat, const float* __restrict__ g,
    const float* __restrict__ bt,
    int Cin, int catOff, size_t a_bstr, size_t b_bstr,
    int segCout, size_t segStride, int qkvMode) {
  __shared__ _Float16 As[64][48];
  __shared__ half2v   Bs[16][132];
  __shared__ float Ac[256], Bc[256];
  const int tid = threadIdx.x;
  const int wv  = tid >> 6;
  const int l   = tid & 63;
  const int wo  = wv >> 1;
  const int wn  = wv & 1;
  const int lr  = l & 15;
  const int lg  = l >> 4;
  const int o0 = blockIdx.y * 64;
  const int zb = blockIdx.x;
  const int z  = zb >> 3;
  const int n0 = (zb & 7) * 128;
  const int s = z >> 2, b = z & 3;
  const int seg = o0 / segCout;
  const int oo  = o0 % segCout;

  const float* XA = (s ? pA1 : pA0) + (size_t)b * a_bstr;
  const float* XB = pB0 ? ((s ? pB1 : pB0) + (size_t)b * b_bstr) : nullptr;
  const bool segB = qkvMode && (seg > 0);

  if (stat) {
    const float* st = stat + (size_t)s * 256 * 2;
    float A = st[tid * 2 + 1] * g[tid];
    Ac[tid] = A;
    Bc[tid] = fmaf(-st[tid * 2 + 0], A, bt[tid]);
  }

  f32x4 acc[2][4];
#pragma unroll
  for (int i = 0; i < 2; ++i)
#pragma unroll
    for (int j = 0; j < 4; ++j) acc[i][j] = (f32x4){0.f, 0.f, 0.f, 0.f};

  for (int kb = 0; kb < Cin; kb += 32) {
    __syncthreads();
#pragma unroll
    for (int j = 0; j < 2; ++j) {
      int idx = j * 256 + tid;
      int o = idx >> 3, c4 = (idx & 7) * 4;
      float4 wvv = *(const float4*)&w[(size_t)(o0 + o) * Cin + kb + c4];
      *(half2v*)&As[o][c4]     = pkrtz(wvv.x, wvv.y);
      *(half2v*)&As[o][c4 + 2] = pkrtz(wvv.z, wvv.w);
    }
#pragma unroll
    for (int j = 0; j < 2; ++j) {
      int idx = j * 256 + tid;
      int rp = idx >> 5, c4 = (idx & 31) * 4;
      int c0 = kb + 2 * rp, c1 = c0 + 1;
      const float* s0; int cc0 = c0;
      const float* s1; int cc1 = c1;
      if (qkvMode) {
        s0 = segB ? XB : XA; s1 = s0;
      } else {
        if (c0 >= catOff) { s0 = XB; cc0 = c0 - catOff; } else s0 = XA;
        if (c1 >= catOff) { s1 = XB; cc1 = c1 - catOff; } else s1 = XA;
      }
      float4 v0 = *(const float4*)&s0[(size_t)cc0 * N + n0 + c4];
      float4 v1 = *(const float4*)&s1[(size_t)cc1 * N + n0 + c4];
      if (stat) {
        float A0 = Ac[c0], B0 = Bc[c0], A1 = Ac[c1], B1 = Bc[c1];
        v0.x = fmaxf(fmaf(v0.x, A0, B0), 0.f);
        v0.y = fmaxf(fmaf(v0.y, A0, B0), 0.f);
        v0.z = fmaxf(fmaf(v0.z, A0, B0), 0.f);
        v0.w = fmaxf(fmaf(v0.w, A0, B0), 0.f);
        v1.x = fmaxf(fmaf(v1.x, A1, B1), 0.f);
        v1.y = fmaxf(fmaf(v1.y, A1, B1), 0.f);
        v1.z = fmaxf(fmaf(v1.z, A1, B1), 0.f);
        v1.w = fmaxf(fmaf(v1.w, A1, B1), 0.f);
      }
      float4 packed;
      packed.x = h2f(pkrtz(v0.x, v1.x));
      packed.y = h2f(pkrtz(v0.y, v1.y));
      packed.z = h2f(pkrtz(v0.z, v1.z));
      packed.w = h2f(pkrtz(v0.w, v1.w));
      *(float4*)&Bs[rp][c4] = packed;
    }
    __syncthreads();
    f16x8 afr0 = *(const f16x8*)&As[wo * 32 + lr][lg * 8];
    f16x8 afr1 = *(const f16x8*)&As[wo * 32 + 16 + lr][lg * 8];
#pragma unroll
    for (int tj = 0; tj < 4; ++tj) {
      int nn = wn * 64 + tj * 16 + lr;
      float4 btmp;
      btmp.x = *(const float*)&Bs[lg * 4 + 0][nn];
      btmp.y = *(const float*)&Bs[lg * 4 + 1][nn];
      btmp.z = *(const float*)&Bs[lg * 4 + 2][nn];
      btmp.w = *(const float*)&Bs[lg * 4 + 3][nn];
      f16x8 bfr = __builtin_bit_cast(f16x8, btmp);
      acc[0][tj] = __builtin_amdgcn_mfma_f32_16x16x32_f16(afr0, bfr, acc[0][tj], 0, 0, 0);
      acc[1][tj] = __builtin_amdgcn_mfma_f32_16x16x32_f16(afr1, bfr, acc[1][tj], 0, 0, 0);
    }
  }
#pragma unroll
  for (int ti = 0; ti < 2; ++ti) {
#pragma unroll
    for (int tj = 0; tj < 4; ++tj) {
      int nn = n0 + wn * 64 + tj * 16 + lr;
#pragma unroll
      for (int r = 0; r < 4; ++r) {
        int lrow = wo * 32 + ti * 16 + lg * 4 + r;
        size_t ob = (size_t)seg * segStride +
                    ((size_t)z * segCout + oo + lrow) * N + nn;
        float v = acc[ti][tj][r] + bias[o0 + lrow];
        if (res) v += res[ob];
        out[ob] = v;
      }
    }
  }
}

// ---------------------------------------------------------------- attention v11: MFMA flash + reg prefetch
// Same as v10 (validated) except staging double-buffers through registers:
// chunk c+1's global loads issue right before compute of chunk c, hiding
// L2/HBM latency under the 16 MFMA + softmax. Barrier count unchanged.
__global__ __launch_bounds__(512) void k_attn(const float* __restrict__ Q,
                                              const float* __restrict__ Kt,
                                              const float* __restrict__ Vt,
                                              float* __restrict__ O) {
  __shared__ _Float16 Klds[128][40];
  __shared__ _Float16 Vlds[32][136];
  const int t  = threadIdx.x;
  const int l  = t & 63, w = t >> 6;
  const int lr = l & 15, lg = l >> 4;
  const int q0 = blockIdx.x * 128 + w * 16;
  const int h  = blockIdx.y;
  const int z  = blockIdx.z;
  const size_t base = (size_t)z * (size_t)(D * N);
  const float* Kg = Kt + base + (size_t)h * N;
  const float* Vg = Vt + base + (size_t)h * N;
  const float scale = 0.17677669529663687f;

  // staging thread roles (fixed per thread)
  const int kk = t & 127, d0s = (t >> 7) * 8;
  const int dv = t & 31,  kos = (t >> 5) * 8;

  f16x8 qfrag;
  {
    float qv[8];
#pragma unroll
    for (int j = 0; j < 8; ++j)
      qv[j] = Q[base + (size_t)((lg * 8 + j) * 4 + h) * N + q0 + lr] * scale;
    float4 qp;
    qp.x = h2f(pkrtz(qv[0], qv[1]));
    qp.y = h2f(pkrtz(qv[2], qv[3]));
    qp.z = h2f(pkrtz(qv[4], qv[5]));
    qp.w = h2f(pkrtz(qv[6], qv[7]));
    qfrag = __builtin_bit_cast(f16x8, qp);
  }

  f32x4 oacc0 = (f32x4){0.f, 0.f, 0.f, 0.f};
  f32x4 oacc1 = (f32x4){0.f, 0.f, 0.f, 0.f};
  float m = -1e30f, lsum = 0.f;

  // prefetch registers (chunk staged next)
  float kv[8];
  float4 vv0, vv1;
  {
    // load chunk 0
#pragma unroll
    for (int j = 0; j < 8; ++j)
      kv[j] = Kg[(size_t)((d0s + j) * 4) * N + kk];
    const float* vp = Vg + (size_t)(dv * 4) * N + kos;
    vv0 = *(const float4*)vp;
    vv1 = *(const float4*)(vp + 4);
  }

  for (int c = 0; c < 8; ++c) {
    __syncthreads();                 // previous compute done; LDS writable
    {
      float4 pk;
      pk.x = h2f(pkrtz(kv[0], kv[1]));
      pk.y = h2f(pkrtz(kv[2], kv[3]));
      pk.z = h2f(pkrtz(kv[4], kv[5]));
      pk.w = h2f(pkrtz(kv[6], kv[7]));
      *(float4*)&Klds[kk][d0s] = pk;
      float4 pv;
      pv.x = h2f(pkrtz(vv0.x, vv0.y)); pv.y = h2f(pkrtz(vv0.z, vv0.w));
      pv.z = h2f(pkrtz(vv1.x, vv1.y)); pv.w = h2f(pkrtz(vv1.z, vv1.w));
      *(float4*)&Vlds[dv][kos] = pv;
    }
    __syncthreads();                 // LDS ready
    if (c < 7) {
      const int k0n = (c + 1) * 128; // prefetch next chunk (hides under compute)
#pragma unroll
      for (int j = 0; j < 8; ++j)
        kv[j] = Kg[(size_t)((d0s + j) * 4) * N + k0n + kk];
      const float* vp = Vg + (size_t)(dv * 4) * N + k0n + kos;
      vv0 = *(const float4*)vp;
      vv1 = *(const float4*)(vp + 4);
    }
#pragma unroll
    for (int kt = 0; kt < 8; ++kt) {
      f16x8 kfrag = *(const f16x8*)&Klds[kt * 16 + lr][lg * 8];
      f32x4 s = __builtin_amdgcn_mfma_f32_16x16x32_f16(
          kfrag, qfrag, (f32x4){0.f, 0.f, 0.f, 0.f}, 0, 0, 0);
      float tmax = fmaxf(fmaxf(s[0], s[1]), fmaxf(s[2], s[3]));
      tmax = fmaxf(tmax, __shfl_xor(tmax, 16, 64));
      tmax = fmaxf(tmax, __shfl_xor(tmax, 32, 64));
      float nm = fmaxf(m, tmax);
      float corr = __expf(m - nm);
      m = nm;
      lsum *= corr;
#pragma unroll
      for (int r = 0; r < 4; ++r) { oacc0[r] *= corr; oacc1[r] *= corr; }
      float p0 = __expf(s[0] - m), p1 = __expf(s[1] - m);
      float p2 = __expf(s[2] - m), p3 = __expf(s[3] - m);
      float ts = p0 + p1 + p2 + p3;
      ts += __shfl_xor(ts, 16, 64);
      ts += __shfl_xor(ts, 32, 64);
      lsum += ts;
      float2 ptmp;
      ptmp.x = h2f(pkrtz(p0, p1));
      ptmp.y = h2f(pkrtz(p2, p3));
      f16x4 pfrag = __builtin_bit_cast(f16x4, ptmp);
      float2 vt0 = *(const float2*)&Vlds[lr][kt * 16 + lg * 4];
      float2 vt1 = *(const float2*)&Vlds[16 + lr][kt * 16 + lg * 4];
      f16x4 vf0 = __builtin_bit_cast(f16x4, vt0);
      f16x4 vf1 = __builtin_bit_cast(f16x4, vt1);
      oacc0 = __builtin_amdgcn_mfma_f32_16x16x16f16(vf0, pfrag, oacc0, 0, 0, 0);
      oacc1 = __builtin_amdgcn_mfma_f32_16x16x16f16(vf1, pfrag, oacc1, 0, 0, 0);
    }
  }
  float invL = 1.f / lsum;
#pragma unroll
  for (int r = 0; r < 4; ++r) {
    int d0 = lg * 4 + r;
    O[base + (size_t)(d0 * 4 + h) * N + q0 + lr] = oacc0[r] * invL;
    int d1 = 16 + lg * 4 + r;
    O[base + (size_t)(d1 * 4 + h) * N + q0 + lr] = oacc1[r] * invL;
  }
}

// ---------------------------------------------------------------- BN stats (single pass)
__global__ __launch_bounds__(256) void k_bnstat(const float* __restrict__ h,
                                                float* __restrict__ stat) {
  int c = blockIdx.x, s = blockIdx.y, t = threadIdx.x;
  __shared__ float red[256], red2[256];
  const float* base = h + ((size_t)s * B * 256 + c) * N;
  float sum = 0, sq = 0;
  for (int b = 0; b < B; ++b)
    for (int i = t; i < N; i += 256) {
      float v = base[(size_t)b * 256 * N + i];
      sum += v; sq = fmaf(v, v, sq);
    }
  red[t] = sum; red2[t] = sq; __syncthreads();
  for (int sft = 128; sft > 0; sft >>= 1) {
    if (t < sft) { red[t] += red[t + sft]; red2[t] += red2[t + sft]; }
    __syncthreads();
  }
  if (t == 0) {
    float mean = red[0] / (float)(B * N);
    float var = fmaxf(red2[0] / (float)(B * N) - mean * mean, 0.f);
    stat[(s * 256 + c) * 2 + 0] = mean;
    stat[(s * 256 + c) * 2 + 1] = 1.f / sqrtf(var + 1e-5f);
  }
}

// ---------------------------------------------------------------- pairwise dist (8-m tile)
__global__ __launch_bounds__(256) void k_dist(const float* __restrict__ d0,
                                              const float* __restrict__ d1,
                                              float* __restrict__ la) {
  __shared__ float xm[8][128];
  __shared__ float n0s[8];
  int m0 = blockIdx.x * 8, b = blockIdx.y, t = threadIdx.x;
  const float* p0 = d0 + (size_t)b * D * N;
  const float* p1 = d1 + (size_t)b * D * N;
  for (int i = t; i < 8 * 128; i += 256) {
    int mm = i >> 7, d = i & 127;
    xm[mm][d] = p0[(size_t)d * N + m0 + mm];
  }
  __syncthreads();
  if (t < 8) {
    float s = 0;
    for (int d = 0; d < 128; ++d) s += xm[t][d] * xm[t][d];
    n0s[t] = s;
  }
  __syncthreads();
  float dot[8][4] = {{0}};
  float n1[4] = {0, 0, 0, 0};
  for (int d = 0; d < 128; ++d) {
    float v[4];
#pragma unroll
    for (int u = 0; u < 4; ++u) {
      v[u] = p1[(size_t)d * N + t + u * 256];
      n1[u] = fmaf(v[u], v[u], n1[u]);
    }
#pragma unroll
    for (int mm = 0; mm < 8; ++mm) {
      float x = xm[mm][d];
#pragma unroll
      for (int u = 0; u < 4; ++u) dot[mm][u] = fmaf(x, v[u], dot[mm][u]);
    }
  }
  for (int mm = 0; mm < 8; ++mm) {
    float* row = la + ((size_t)b * N + m0 + mm) * N;
#pragma unroll
    for (int u = 0; u < 4; ++u) {
      float dist2 = fmaxf(n0s[mm] + n1[u] - 2.f * dot[mm][u], 1e-30f);
      row[t + u * 256] = -sqrtf(dist2);
    }
  }
}

// ---------------------------------------------------------------- sinkhorn row v2: wave-per-row (R21, validated)
__global__ __launch_bounds__(256) void k_row_r(const float* __restrict__ l0,
                                               const float* __restrict__ cvec,
                                               float* __restrict__ r,
                                               int useC) {
  const int t = threadIdx.x;
  const int l = t & 63, wv = t >> 6;
  const int bm = blockIdx.x * 4 + wv;   // over B*N
  const int b = bm >> 10;
  const float* row = l0 + (size_t)bm * N;
  const float* cl = cvec + (size_t)b * N;
  float mx = -1e30f, s = 0.f;
#pragma unroll
  for (int i = 0; i < 4; ++i) {
    int n4 = l * 4 + i * 256;
    float4 v = *(const float4*)&row[n4];
    if (useC) {
      float4 c4 = *(const float4*)&cl[n4];
      v.x -= c4.x; v.y -= c4.y; v.z -= c4.z; v.w -= c4.w;
    }
    float tm = fmaxf(fmaxf(v.x, v.y), fmaxf(v.z, v.w));
    if (tm > mx) { s *= __expf(mx - tm); mx = tm; }
    s += __expf(v.x - mx) + __expf(v.y - mx) + __expf(v.z - mx) + __expf(v.w - mx);
  }
#pragma unroll
  for (int sft = 1; sft < 64; sft <<= 1) {
    float m2 = __shfl_xor(mx, sft, 64);
    float s2 = __shfl_xor(s, sft, 64);
    float nm = fmaxf(mx, m2);
    s = s * __expf(mx - nm) + s2 * __expf(m2 - nm);
    mx = nm;
  }
  if (l == 0) r[bm] = mx + __logf(s);
}

__global__ __launch_bounds__(256) void k_col_part(const float* __restrict__ l0,
                                                  const float* __restrict__ r,
                                                  float* __restrict__ pmax,
                                                  float* __restrict__ psum) {
  int t = threadIdx.x;
  int n = blockIdx.x * 256 + t;
  int p = blockIdx.y, b = blockIdx.z;
  const float* base = l0 + ((size_t)b * N + p * 32) * N + n;
  const float* rr = r + (size_t)b * N + p * 32;
  float mx = -1e30f, s = 0;
  for (int m = 0; m < 32; ++m) {
    float v = base[(size_t)m * N] - rr[m];
    if (v > mx) { s = s * __expf(mx - v) + 1.f; mx = v; }
    else s += __expf(v - mx);
  }
  pmax[((size_t)b * 32 + p) * N + n] = mx;
  psum[((size_t)b * 32 + p) * N + n] = s;
}

// ---------------------------------------------------------------- col finalize v2: 4-way p-split (R21, validated)
__global__ __launch_bounds__(256) void k_col_fin(const float* __restrict__ pmax,
                                                 const float* __restrict__ psum,
                                                 float* __restrict__ cvec) {
  __shared__ float smx[4][64], ssm[4][64];
  const int blk = blockIdx.x;            // 0..16*B-1
  const int b = blk >> 4;
  const int n0 = (blk & 15) * 64;
  const int tn = threadIdx.x & 63, tp = threadIdx.x >> 6;
  const int n = n0 + tn;
  float mx = -1e30f, s = 0.f;
#pragma unroll
  for (int pi = 0; pi < 8; ++pi) {
    int p = tp * 8 + pi;
    float m2 = pmax[((size_t)b * 32 + p) * N + n];
    float s2 = psum[((size_t)b * 32 + p) * N + n];
    float nm = fmaxf(mx, m2);
    s = s * __expf(mx - nm) + s2 * __expf(m2 - nm);
    mx = nm;
  }
  smx[tp][tn] = mx; ssm[tp][tn] = s;
  __syncthreads();
  if (tp == 0) {
#pragma unroll
    for (int q = 1; q < 4; ++q) {
      float m2 = smx[q][tn], s2 = ssm[q][tn];
      float nm = fmaxf(mx, m2);
      s = s * __expf(mx - nm) + s2 * __expf(m2 - nm);
      mx = nm;
    }
    cvec[(size_t)b * N + n] = mx + __logf(s);
  }
}

// ---------------------------------------------------------------- rodrigues + transform
__global__ __launch_bounds__(256) void k_rod(const float* __restrict__ pose,
                                             const float* __restrict__ p3d,
                                             float* __restrict__ p3dt) {
  int b = blockIdx.y;
  int n = blockIdx.x * 256 + threadIdx.x;
  const float* aa = pose + b * 6;
  float ax = aa[0], ay = aa[1], az = aa[2];
  float th = fmaxf(sqrtf(ax * ax + ay * ay + az * az), 1e-8f);
  float rx = ax / th, ry = ay / th, rz = az / th;
  float c = cosf(th), s = sinf(th), oc = 1.f - c;
  float R00 = c + oc * rx * rx,      R01 = oc * rx * ry - s * rz, R02 = oc * rx * rz + s * ry;
  float R10 = oc * ry * rx + s * rz, R11 = c + oc * ry * ry,      R12 = oc * ry * rz - s * rx;
  float R20 = oc * rz * rx - s * ry, R21 = oc * rz * ry + s * rx, R22 = c + oc * rz * rz;
  const float* p = p3d + ((size_t)b * N + n) * 3;
  float x = p[0], y = p[1], z = p[2];
  float X = R00 * x + R01 * y + R02 * z + aa[3];
  float Y = R10 * x + R11 * y + R12 * z + aa[4];
  float Z = R20 * x + R21 * y + R22 * z + aa[5];
  float inr = 1.f / sqrtf(X * X + Y * Y + Z * Z);
  float* o = p3dt + ((size_t)b * N + n) * 3;
  o[0] = X * inr; o[1] = Y * inr; o[2] = Z * inr;
}

// ---------------------------------------------------------------- final error (applies r,c offsets)
__global__ __launch_bounds__(256) void k_err(const float* __restrict__ l0,
                                             const float* __restrict__ r,
                                             const float* __restrict__ cvec,
                                             const float* __restrict__ f2,
                                             const float* __restrict__ p3dt,
                                             float* __restrict__ rowsum) {
  __shared__ float red[256];
  int m = blockIdx.x, b = blockIdx.y, t = threadIdx.x;
  const float* row = l0 + ((size_t)b * N + m) * N;
  const float* cl = cvec + (size_t)b * N;
  const float rm = r[(size_t)b * N + m];
  const float* f = f2 + ((size_t)b * N + m) * 3;
  float fx = f[0], fy = f[1], fz = f[2];
  float s = 0;
  for (int n = t; n < N; n += 256) {
    const float* pp = p3dt + ((size_t)b * N + n) * 3;
    float dot = fx * pp[0] + fy * pp[1] + fz * pp[2];
    s += __expf(row[n] - rm - cl[n]) * (1.f - dot);
  }
  red[t] = s; __syncthreads();
  for (int sft = 128; sft > 0; sft >>= 1) {
    if (t < sft) red[t] += red[t + sft];
    __syncthreads();
  }
  if (t == 0) rowsum[(size_t)b * N + m] = red[0];
}

__global__ __launch_bounds__(256) void k_err_fin(const float* __restrict__ rowsum,
                                                 float* __restrict__ out) {
  __shared__ float red[256];
  int b = blockIdx.x, t = threadIdx.x;
  float s = 0;
  for (int i = t; i < N; i += 256) s += rowsum[(size_t)b * N + i];
  red[t] = s; __syncthreads();
  for (int sft = 128; sft > 0; sft >>= 1) {
    if (t < sft) red[t] += red[t + sft];
    __syncthreads();
  }
  if (t == 0) out[b] = red[0];
}

// ================================================================= host
extern "C" void kernel_launch(void* const* d_in, const int* in_sizes, int n_in,
                              void* d_out, int out_size, void* d_ws, size_t ws_size,
                              hipStream_t stream) {
  const float* p2d     = (const float*)d_in[0];
  const float* p3d     = (const float*)d_in[1];
  const float* pose    = (const float*)d_in[2];
  const float* enc2d_w = (const float*)d_in[3];
  const float* enc2d_b = (const float*)d_in[4];
  const float* enc3d_w = (const float*)d_in[5];
  const float* enc3d_b = (const float*)d_in[6];
  const float* proj_w  = (const float*)d_in[7];
  const float* proj_b  = (const float*)d_in[8];
  const float* merge_w = (const float*)d_in[9];
  const float* merge_b = (const float*)d_in[10];
  const float* mlp1_w  = (const float*)d_in[11];
  const float* mlp1_b  = (const float*)d_in[12];
  const float* bn_g    = (const float*)d_in[13];
  const float* bn_b    = (const float*)d_in[14];
  const float* mlp2_w  = (const float*)d_in[15];
  const float* mlp2_b  = (const float*)d_in[16];

  float* W = (float*)d_ws;
  size_t off = 0;
  auto alloc = [&](size_t nelem) { float* p = W + off; off += nelem; return p; };
  const size_t SET = (size_t)B * D * N;
  float* f2    = alloc((size_t)B * N * 3);
  float* p3dt  = alloc((size_t)B * N * 3);
  float* descA = alloc(2 * SET);
  float* descB = alloc(2 * SET);
  float* qkv   = alloc(3 * 2 * SET);
  float* attnb = alloc(2 * SET);
  float* hb    = alloc((size_t)2 * B * 256 * N);
  float* stat  = alloc(2 * 256 * 2);
  float* la    = alloc((size_t)B * N * N);
  float* pmax  = alloc((size_t)B * 32 * N);
  float* psum  = alloc((size_t)B * 32 * N);
  float* cvec  = alloc((size_t)B * N);
  float* rvec  = alloc((size_t)B * N);
  float* rowsum= alloc((size_t)B * N);
  float* wcomb = alloc((size_t)6 * 256 * 256);
  float* bcomb = alloc((size_t)6 * 256);
  (void)ws_size; (void)in_sizes; (void)n_in; (void)out_size;

  float* Qb = qkv;
  float* Kb = qkv + 2 * SET;
  float* Vb = qkv + 4 * SET;
  const size_t DS = (size_t)D * N;

  k_fold<<<dim3(256, 6), 128, 0, stream>>>(mlp1_w, mlp1_b, merge_w, merge_b,
                                           wcomb, bcomb);

  k_norm2d<<<(B * N) / 256, 256, 0, stream>>>(p2d, f2);
  k_encode<<<dim3(N / 4, B), 256, 0, stream>>>(f2, enc2d_w, enc2d_b, descA);
  k_encode<<<dim3(N / 4, B), 256, 0, stream>>>(p3d, enc3d_w, enc3d_b, descA + SET);

  float* dc = descA;
  float* dn = descB;
  for (int i = 0; i < 6; ++i) {
    int cross = (i & 1);
    const float* pw = proj_w + (size_t)i * 3 * D * D;
    const float* pb = proj_b + (size_t)i * 3 * D;
    float* d0 = dc;
    float* d1 = dc + SET;
    const float* sA = cross ? d1 : d0;
    const float* sB = cross ? d0 : d1;

    k_gemm<<<dim3(64, 6), 256, 0, stream>>>(
        d0, d1, sA, sB, pw, pb, nullptr, qkv, nullptr, nullptr, nullptr,
        D, D, DS, DS, D, 2 * SET, 1);
    k_attn<<<dim3(N / 128, NH, 2 * B), 512, 0, stream>>>(Qb, Kb, Vb, attnb);
    k_gemm<<<dim3(64, 4), 256, 0, stream>>>(
        dc, dc + SET, attnb, attnb + SET, wcomb + (size_t)i * 256 * 256,
        bcomb + (size_t)i * 256, nullptr, hb, nullptr, nullptr, nullptr,
        256, 128, DS, DS, 256, 0, 0);
    k_bnstat<<<dim3(256, 2), 256, 0, stream>>>(hb, stat);
    k_gemm<<<dim3(64, 2), 256, 0, stream>>>(
        hb, hb + (size_t)B * 256 * N, nullptr, nullptr,
        mlp2_w + (size_t)i * D * 256, mlp2_b + (size_t)i * D, dc, dn,
        stat, bn_g + (size_t)i * 256, bn_b + (size_t)i * 256,
        256, 256, (size_t)256 * N, 0, D, 0, 0);
    float* tmp = dc; dc = dn; dn = tmp;
  }

  k_dist<<<dim3(N / 8, B), 256, 0, stream>>>(dc, dc + SET, la);
  for (int it = 0; it < 10; ++it) {
    k_row_r<<<(B * N) / 4, 256, 0, stream>>>(la, cvec, rvec, it > 0 ? 1 : 0);
    k_col_part<<<dim3(N / 256, 32, B), 256, 0, stream>>>(la, rvec, pmax, psum);
    k_col_fin<<<16 * B, 256, 0, stream>>>(pmax, psum, cvec);
  }
  k_rod<<<dim3(N / 256, B), 256, 0, stream>>>(pose, p3d, p3dt);
  k_err<<<dim3(N, B), 256, 0, stream>>>(la, rvec, cvec, f2, p3dt, rowsum);
  k_err_fin<<<B, 256, 0, stream>>>(rowsum, (float*)d_out);
}

// Round 24
// 763.575 us; speedup vs baseline: 1.0824x; 1.0120x over previous
//
#include <hip/hip_runtime.h>
#include <hip/hip_bf16.h>

constexpr int B   = 4;
constexpr int N   = 1024;
constexpr int D   = 128;
constexpr int KNN = 10;
constexpr int NH  = 4;

typedef _Float16 half2v __attribute__((ext_vector_type(2)));
typedef _Float16 f16x4  __attribute__((ext_vector_type(4)));
typedef _Float16 f16x8  __attribute__((ext_vector_type(8)));
typedef float    f32x4  __attribute__((ext_vector_type(4)));

static __device__ __forceinline__ half2v pkrtz(float a, float b) {
  return __builtin_bit_cast(half2v, __builtin_amdgcn_cvt_pkrtz(a, b));
}
static __device__ __forceinline__ float h2f(half2v h) {
  return __builtin_bit_cast(float, h);
}

// ---------------------------------------------------------------- norm p2d
__global__ __launch_bounds__(256) void k_norm2d(const float* __restrict__ p2d,
                                                float* __restrict__ f2) {
  int i = blockIdx.x * 256 + threadIdx.x;  // over B*N
  const float* p = p2d + (size_t)i * 3;
  float x = p[0], y = p[1], z = p[2];
  float inr = 1.f / sqrtf(x * x + y * y + z * z);
  float* o = f2 + (size_t)i * 3;
  o[0] = x * inr; o[1] = y * inr; o[2] = z * inr;
}

// ---------------------------------------------------------------- merge-fold precompute (R20, validated)
__global__ __launch_bounds__(128) void k_fold(const float* __restrict__ mlp1_w,
                                              const float* __restrict__ mlp1_b,
                                              const float* __restrict__ merge_w,
                                              const float* __restrict__ merge_b,
                                              float* __restrict__ wcomb,
                                              float* __restrict__ bcomb) {
  __shared__ float red[128];
  const int o = blockIdx.x;        // 0..255
  const int i = blockIdx.y;        // layer 0..5
  const int c = threadIdx.x;       // 0..127
  const float* W1 = mlp1_w + (size_t)i * 256 * 256 + (size_t)o * 256;
  const float* Wm = merge_w + (size_t)i * 128 * 128;
  float* out = wcomb + (size_t)i * 256 * 256 + (size_t)o * 256;
  out[c] = W1[c];
  float acc = 0.f;
#pragma unroll 8
  for (int k = 0; k < 128; ++k)
    acc = fmaf(W1[128 + k], Wm[(size_t)k * 128 + c], acc);
  out[128 + c] = acc;
  red[c] = W1[128 + c] * merge_b[i * 128 + c];
  __syncthreads();
  for (int s = 64; s > 0; s >>= 1) {
    if (c < s) red[c] += red[c + s];
    __syncthreads();
  }
  if (c == 0) bcomb[i * 256 + o] = mlp1_b[i * 256 + o] + red[0];
}

// ---------------------------------------------------------------- KNN encode v2: wave-per-query (R17, validated)
__global__ __launch_bounds__(256) void k_encode(const float* __restrict__ pts,
                                                const float* __restrict__ w,
                                                const float* __restrict__ bias,
                                                float* __restrict__ desc) {
  __shared__ float Px[N], Py[N], Pz[N], Xx[N];
  const int t = threadIdx.x;
  const int l = t & 63, wv = t >> 6;
  const int n = blockIdx.x * 4 + wv;
  const int b = blockIdx.y;
  const float* pb = pts + (size_t)b * N * 3;
  for (int i = t; i < N; i += 256) {
    float x = pb[i * 3 + 0], y = pb[i * 3 + 1], z = pb[i * 3 + 2];
    Px[i] = x; Py[i] = y; Pz[i] = z;
    Xx[i] = x * x + y * y + z * z;
  }
  __syncthreads();
  const float cx = Px[n], cy = Py[n], cz = Pz[n], cxx = Xx[n];
  float dist[16];
#pragma unroll
  for (int i = 0; i < 16; ++i) {
    int j = i * 64 + l;
    float ip = cx * Px[j] + cy * Py[j] + cz * Pz[j];
    dist[i] = 2.f * ip - cxx - Xx[j];
  }
  float sx = 0.f, sy = 0.f, sz = 0.f;
#pragma unroll
  for (int kk = 0; kk < KNN; ++kk) {
    float bv = dist[0]; int bi = l;
#pragma unroll
    for (int i = 1; i < 16; ++i) {
      if (dist[i] > bv) { bv = dist[i]; bi = i * 64 + l; }
    }
#pragma unroll
    for (int sft = 1; sft < 64; sft <<= 1) {
      float v2 = __shfl_xor(bv, sft, 64);
      int   i2 = __shfl_xor(bi, sft, 64);
      if (v2 > bv || (v2 == bv && i2 < bi)) { bv = v2; bi = i2; }
    }
    sx += Px[bi]; sy += Py[bi]; sz += Pz[bi];
    if ((bi & 63) == l) {
      int io = bi >> 6;
#pragma unroll
      for (int i = 0; i < 16; ++i)
        if (i == io) dist[i] = -3.0e38f;
    }
  }
  const float invk = 1.f / KNN;
  float feat[6];
  feat[0] = sx * invk - cx; feat[1] = sy * invk - cy; feat[2] = sz * invk - cz;
  feat[3] = cx; feat[4] = cy; feat[5] = cz;
#pragma unroll
  for (int rep = 0; rep < 2; ++rep) {
    int c = rep * 64 + l;
    const float* wr = w + c * 6;
    float a = bias[c];
#pragma unroll
    for (int j = 0; j < 6; ++j) a += wr[j] * feat[j];
    desc[((size_t)b * D + c) * N + n] = a;
  }
}

// ---------------------------------------------------------------- tiled GEMM conv v3: MFMA f16 (R15)
// + optional BN-stat partial fusion (pstat != null): per-block (sum, sumsq)
// per channel over the block's 128 cols, written to pstat[set][ch][blk][2].
__global__ __launch_bounds__(256) void k_gemm(
    const float* __restrict__ pA0, const float* __restrict__ pA1,
    const float* __restrict__ pB0, const float* __restrict__ pB1,
    const float* __restrict__ w, const float* __restrict__ bias,
    const float* __restrict__ res, float* __restrict__ out,
    const float* __restrict__ stat, const float* __restrict__ g,
    const float* __restrict__ bt, float* __restrict__ pstat,
    int Cin, int catOff, size_t a_bstr, size_t b_bstr,
    int segCout, size_t segStride, int qkvMode) {
  __shared__ _Float16 As[64][48];
  __shared__ half2v   Bs[16][132];
  __shared__ float Ac[256], Bc[256];
  __shared__ float PS[2][64], PQ[2][64];
  const int tid = threadIdx.x;
  const int wv  = tid >> 6;
  const int l   = tid & 63;
  const int wo  = wv >> 1;
  const int wn  = wv & 1;
  const int lr  = l & 15;
  const int lg  = l >> 4;
  const int o0 = blockIdx.y * 64;
  const int zb = blockIdx.x;
  const int z  = zb >> 3;
  const int n0 = (zb & 7) * 128;
  const int s = z >> 2, b = z & 3;
  const int seg = o0 / segCout;
  const int oo  = o0 % segCout;

  const float* XA = (s ? pA1 : pA0) + (size_t)b * a_bstr;
  const float* XB = pB0 ? ((s ? pB1 : pB0) + (size_t)b * b_bstr) : nullptr;
  const bool segB = qkvMode && (seg > 0);

  if (stat) {
    const float* st = stat + (size_t)s * 256 * 2;
    float A = st[tid * 2 + 1] * g[tid];
    Ac[tid] = A;
    Bc[tid] = fmaf(-st[tid * 2 + 0], A, bt[tid]);
  }

  f32x4 acc[2][4];
#pragma unroll
  for (int i = 0; i < 2; ++i)
#pragma unroll
    for (int j = 0; j < 4; ++j) acc[i][j] = (f32x4){0.f, 0.f, 0.f, 0.f};

  for (int kb = 0; kb < Cin; kb += 32) {
    __syncthreads();
#pragma unroll
    for (int j = 0; j < 2; ++j) {
      int idx = j * 256 + tid;
      int o = idx >> 3, c4 = (idx & 7) * 4;
      float4 wvv = *(const float4*)&w[(size_t)(o0 + o) * Cin + kb + c4];
      *(half2v*)&As[o][c4]     = pkrtz(wvv.x, wvv.y);
      *(half2v*)&As[o][c4 + 2] = pkrtz(wvv.z, wvv.w);
    }
#pragma unroll
    for (int j = 0; j < 2; ++j) {
      int idx = j * 256 + tid;
      int rp = idx >> 5, c4 = (idx & 31) * 4;
      int c0 = kb + 2 * rp, c1 = c0 + 1;
      const float* s0; int cc0 = c0;
      const float* s1; int cc1 = c1;
      if (qkvMode) {
        s0 = segB ? XB : XA; s1 = s0;
      } else {
        if (c0 >= catOff) { s0 = XB; cc0 = c0 - catOff; } else s0 = XA;
        if (c1 >= catOff) { s1 = XB; cc1 = c1 - catOff; } else s1 = XA;
      }
      float4 v0 = *(const float4*)&s0[(size_t)cc0 * N + n0 + c4];
      float4 v1 = *(const float4*)&s1[(size_t)cc1 * N + n0 + c4];
      if (stat) {
        float A0 = Ac[c0], B0 = Bc[c0], A1 = Ac[c1], B1 = Bc[c1];
        v0.x = fmaxf(fmaf(v0.x, A0, B0), 0.f);
        v0.y = fmaxf(fmaf(v0.y, A0, B0), 0.f);
        v0.z = fmaxf(fmaf(v0.z, A0, B0), 0.f);
        v0.w = fmaxf(fmaf(v0.w, A0, B0), 0.f);
        v1.x = fmaxf(fmaf(v1.x, A1, B1), 0.f);
        v1.y = fmaxf(fmaf(v1.y, A1, B1), 0.f);
        v1.z = fmaxf(fmaf(v1.z, A1, B1), 0.f);
        v1.w = fmaxf(fmaf(v1.w, A1, B1), 0.f);
      }
      float4 packed;
      packed.x = h2f(pkrtz(v0.x, v1.x));
      packed.y = h2f(pkrtz(v0.y, v1.y));
      packed.z = h2f(pkrtz(v0.z, v1.z));
      packed.w = h2f(pkrtz(v0.w, v1.w));
      *(float4*)&Bs[rp][c4] = packed;
    }
    __syncthreads();
    f16x8 afr0 = *(const f16x8*)&As[wo * 32 + lr][lg * 8];
    f16x8 afr1 = *(const f16x8*)&As[wo * 32 + 16 + lr][lg * 8];
#pragma unroll
    for (int tj = 0; tj < 4; ++tj) {
      int nn = wn * 64 + tj * 16 + lr;
      float4 btmp;
      btmp.x = *(const float*)&Bs[lg * 4 + 0][nn];
      btmp.y = *(const float*)&Bs[lg * 4 + 1][nn];
      btmp.z = *(const float*)&Bs[lg * 4 + 2][nn];
      btmp.w = *(const float*)&Bs[lg * 4 + 3][nn];
      f16x8 bfr = __builtin_bit_cast(f16x8, btmp);
      acc[0][tj] = __builtin_amdgcn_mfma_f32_16x16x32_f16(afr0, bfr, acc[0][tj], 0, 0, 0);
      acc[1][tj] = __builtin_amdgcn_mfma_f32_16x16x32_f16(afr1, bfr, acc[1][tj], 0, 0, 0);
    }
  }
  float rs[2][4] = {{0.f, 0.f, 0.f, 0.f}, {0.f, 0.f, 0.f, 0.f}};
  float rq[2][4] = {{0.f, 0.f, 0.f, 0.f}, {0.f, 0.f, 0.f, 0.f}};
#pragma unroll
  for (int ti = 0; ti < 2; ++ti) {
#pragma unroll
    for (int tj = 0; tj < 4; ++tj) {
      int nn = n0 + wn * 64 + tj * 16 + lr;
#pragma unroll
      for (int r = 0; r < 4; ++r) {
        int lrow = wo * 32 + ti * 16 + lg * 4 + r;
        size_t ob = (size_t)seg * segStride +
                    ((size_t)z * segCout + oo + lrow) * N + nn;
        float v = acc[ti][tj][r] + bias[o0 + lrow];
        if (res) v += res[ob];
        out[ob] = v;
        if (pstat) { rs[ti][r] += v; rq[ti][r] = fmaf(v, v, rq[ti][r]); }
      }
    }
  }
  if (pstat) {
    // reduce over the 16 lr lanes (shfl stays within 16-lane group)
#pragma unroll
    for (int ti = 0; ti < 2; ++ti) {
#pragma unroll
      for (int r = 0; r < 4; ++r) {
        float s1 = rs[ti][r], s2 = rq[ti][r];
#pragma unroll
        for (int sft = 1; sft < 16; sft <<= 1) {
          s1 += __shfl_xor(s1, sft, 64);
          s2 += __shfl_xor(s2, sft, 64);
        }
        if (lr == 0) {
          int row = wo * 32 + ti * 16 + lg * 4 + r;
          PS[wn][row] = s1; PQ[wn][row] = s2;
        }
      }
    }
    __syncthreads();
    if (tid < 64) {
      int row = tid;
      float s1 = PS[0][row] + PS[1][row];
      float s2 = PQ[0][row] + PQ[1][row];
      int ch = o0 + row;
      int blk = ((z & 3) << 3) | (zb & 7);     // b*8 + nblock, 0..31
      size_t pb_ = (((size_t)s * 256 + ch) * 32 + blk) * 2;
      pstat[pb_] = s1; pstat[pb_ + 1] = s2;
    }
  }
}

// ---------------------------------------------------------------- BN stat combine (32 partials -> mean/invstd)
__global__ __launch_bounds__(256) void k_bnstat_c(const float* __restrict__ pstat,
                                                  float* __restrict__ stat) {
  const int ch = threadIdx.x;
  const int s = blockIdx.x;
  const float* p = pstat + (((size_t)s * 256 + ch) * 32) * 2;
  float s1 = 0.f, s2 = 0.f;
#pragma unroll 8
  for (int i = 0; i < 32; ++i) { s1 += p[i * 2]; s2 += p[i * 2 + 1]; }
  float mean = s1 / (float)(B * N);
  float var = fmaxf(s2 / (float)(B * N) - mean * mean, 0.f);
  stat[(s * 256 + ch) * 2 + 0] = mean;
  stat[(s * 256 + ch) * 2 + 1] = 1.f / sqrtf(var + 1e-5f);
}

// ---------------------------------------------------------------- attention v11: MFMA flash + reg prefetch (R23, validated)
__global__ __launch_bounds__(512) void k_attn(const float* __restrict__ Q,
                                              const float* __restrict__ Kt,
                                              const float* __restrict__ Vt,
                                              float* __restrict__ O) {
  __shared__ _Float16 Klds[128][40];
  __shared__ _Float16 Vlds[32][136];
  const int t  = threadIdx.x;
  const int l  = t & 63, w = t >> 6;
  const int lr = l & 15, lg = l >> 4;
  const int q0 = blockIdx.x * 128 + w * 16;
  const int h  = blockIdx.y;
  const int z  = blockIdx.z;
  const size_t base = (size_t)z * (size_t)(D * N);
  const float* Kg = Kt + base + (size_t)h * N;
  const float* Vg = Vt + base + (size_t)h * N;
  const float scale = 0.17677669529663687f;

  const int kk = t & 127, d0s = (t >> 7) * 8;
  const int dv = t & 31,  kos = (t >> 5) * 8;

  f16x8 qfrag;
  {
    float qv[8];
#pragma unroll
    for (int j = 0; j < 8; ++j)
      qv[j] = Q[base + (size_t)((lg * 8 + j) * 4 + h) * N + q0 + lr] * scale;
    float4 qp;
    qp.x = h2f(pkrtz(qv[0], qv[1]));
    qp.y = h2f(pkrtz(qv[2], qv[3]));
    qp.z = h2f(pkrtz(qv[4], qv[5]));
    qp.w = h2f(pkrtz(qv[6], qv[7]));
    qfrag = __builtin_bit_cast(f16x8, qp);
  }

  f32x4 oacc0 = (f32x4){0.f, 0.f, 0.f, 0.f};
  f32x4 oacc1 = (f32x4){0.f, 0.f, 0.f, 0.f};
  float m = -1e30f, lsum = 0.f;

  float kv[8];
  float4 vv0, vv1;
  {
#pragma unroll
    for (int j = 0; j < 8; ++j)
      kv[j] = Kg[(size_t)((d0s + j) * 4) * N + kk];
    const float* vp = Vg + (size_t)(dv * 4) * N + kos;
    vv0 = *(const float4*)vp;
    vv1 = *(const float4*)(vp + 4);
  }

  for (int c = 0; c < 8; ++c) {
    __syncthreads();
    {
      float4 pk;
      pk.x = h2f(pkrtz(kv[0], kv[1]));
      pk.y = h2f(pkrtz(kv[2], kv[3]));
      pk.z = h2f(pkrtz(kv[4], kv[5]));
      pk.w = h2f(pkrtz(kv[6], kv[7]));
      *(float4*)&Klds[kk][d0s] = pk;
      float4 pv;
      pv.x = h2f(pkrtz(vv0.x, vv0.y)); pv.y = h2f(pkrtz(vv0.z, vv0.w));
      pv.z = h2f(pkrtz(vv1.x, vv1.y)); pv.w = h2f(pkrtz(vv1.z, vv1.w));
      *(float4*)&Vlds[dv][kos] = pv;
    }
    __syncthreads();
    if (c < 7) {
      const int k0n = (c + 1) * 128;
#pragma unroll
      for (int j = 0; j < 8; ++j)
        kv[j] = Kg[(size_t)((d0s + j) * 4) * N + k0n + kk];
      const float* vp = Vg + (size_t)(dv * 4) * N + k0n + kos;
      vv0 = *(const float4*)vp;
      vv1 = *(const float4*)(vp + 4);
    }
#pragma unroll
    for (int kt = 0; kt < 8; ++kt) {
      f16x8 kfrag = *(const f16x8*)&Klds[kt * 16 + lr][lg * 8];
      f32x4 s = __builtin_amdgcn_mfma_f32_16x16x32_f16(
          kfrag, qfrag, (f32x4){0.f, 0.f, 0.f, 0.f}, 0, 0, 0);
      float tmax = fmaxf(fmaxf(s[0], s[1]), fmaxf(s[2], s[3]));
      tmax = fmaxf(tmax, __shfl_xor(tmax, 16, 64));
      tmax = fmaxf(tmax, __shfl_xor(tmax, 32, 64));
      float nm = fmaxf(m, tmax);
      float corr = __expf(m - nm);
      m = nm;
      lsum *= corr;
#pragma unroll
      for (int r = 0; r < 4; ++r) { oacc0[r] *= corr; oacc1[r] *= corr; }
      float p0 = __expf(s[0] - m), p1 = __expf(s[1] - m);
      float p2 = __expf(s[2] - m), p3 = __expf(s[3] - m);
      float ts = p0 + p1 + p2 + p3;
      ts += __shfl_xor(ts, 16, 64);
      ts += __shfl_xor(ts, 32, 64);
      lsum += ts;
      float2 ptmp;
      ptmp.x = h2f(pkrtz(p0, p1));
      ptmp.y = h2f(pkrtz(p2, p3));
      f16x4 pfrag = __builtin_bit_cast(f16x4, ptmp);
      float2 vt0 = *(const float2*)&Vlds[lr][kt * 16 + lg * 4];
      float2 vt1 = *(const float2*)&Vlds[16 + lr][kt * 16 + lg * 4];
      f16x4 vf0 = __builtin_bit_cast(f16x4, vt0);
      f16x4 vf1 = __builtin_bit_cast(f16x4, vt1);
      oacc0 = __builtin_amdgcn_mfma_f32_16x16x16f16(vf0, pfrag, oacc0, 0, 0, 0);
      oacc1 = __builtin_amdgcn_mfma_f32_16x16x16f16(vf1, pfrag, oacc1, 0, 0, 0);
    }
  }
  float invL = 1.f / lsum;
#pragma unroll
  for (int r = 0; r < 4; ++r) {
    int d0 = lg * 4 + r;
    O[base + (size_t)(d0 * 4 + h) * N + q0 + lr] = oacc0[r] * invL;
    int d1 = 16 + lg * 4 + r;
    O[base + (size_t)(d1 * 4 + h) * N + q0 + lr] = oacc1[r] * invL;
  }
}

// ---------------------------------------------------------------- pairwise dist (8-m tile)
__global__ __launch_bounds__(256) void k_dist(const float* __restrict__ d0,
                                              const float* __restrict__ d1,
                                              float* __restrict__ la) {
  __shared__ float xm[8][128];
  __shared__ float n0s[8];
  int m0 = blockIdx.x * 8, b = blockIdx.y, t = threadIdx.x;
  const float* p0 = d0 + (size_t)b * D * N;
  const float* p1 = d1 + (size_t)b * D * N;
  for (int i = t; i < 8 * 128; i += 256) {
    int mm = i >> 7, d = i & 127;
    xm[mm][d] = p0[(size_t)d * N + m0 + mm];
  }
  __syncthreads();
  if (t < 8) {
    float s = 0;
    for (int d = 0; d < 128; ++d) s += xm[t][d] * xm[t][d];
    n0s[t] = s;
  }
  __syncthreads();
  float dot[8][4] = {{0}};
  float n1[4] = {0, 0, 0, 0};
  for (int d = 0; d < 128; ++d) {
    float v[4];
#pragma unroll
    for (int u = 0; u < 4; ++u) {
      v[u] = p1[(size_t)d * N + t + u * 256];
      n1[u] = fmaf(v[u], v[u], n1[u]);
    }
#pragma unroll
    for (int mm = 0; mm < 8; ++mm) {
      float x = xm[mm][d];
#pragma unroll
      for (int u = 0; u < 4; ++u) dot[mm][u] = fmaf(x, v[u], dot[mm][u]);
    }
  }
  for (int mm = 0; mm < 8; ++mm) {
    float* row = la + ((size_t)b * N + m0 + mm) * N;
#pragma unroll
    for (int u = 0; u < 4; ++u) {
      float dist2 = fmaxf(n0s[mm] + n1[u] - 2.f * dot[mm][u], 1e-30f);
      row[t + u * 256] = -sqrtf(dist2);
    }
  }
}

// ---------------------------------------------------------------- sinkhorn row v2: wave-per-row (R21, validated)
__global__ __launch_bounds__(256) void k_row_r(const float* __restrict__ l0,
                                               const float* __restrict__ cvec,
                                               float* __restrict__ r,
                                               int useC) {
  const int t = threadIdx.x;
  const int l = t & 63, wv = t >> 6;
  const int bm = blockIdx.x * 4 + wv;   // over B*N
  const int b = bm >> 10;
  const float* row = l0 + (size_t)bm * N;
  const float* cl = cvec + (size_t)b * N;
  float mx = -1e30f, s = 0.f;
#pragma unroll
  for (int i = 0; i < 4; ++i) {
    int n4 = l * 4 + i * 256;
    float4 v = *(const float4*)&row[n4];
    if (useC) {
      float4 c4 = *(const float4*)&cl[n4];
      v.x -= c4.x; v.y -= c4.y; v.z -= c4.z; v.w -= c4.w;
    }
    float tm = fmaxf(fmaxf(v.x, v.y), fmaxf(v.z, v.w));
    if (tm > mx) { s *= __expf(mx - tm); mx = tm; }
    s += __expf(v.x - mx) + __expf(v.y - mx) + __expf(v.z - mx) + __expf(v.w - mx);
  }
#pragma unroll
  for (int sft = 1; sft < 64; sft <<= 1) {
    float m2 = __shfl_xor(mx, sft, 64);
    float s2 = __shfl_xor(s, sft, 64);
    float nm = fmaxf(mx, m2);
    s = s * __expf(mx - nm) + s2 * __expf(m2 - nm);
    mx = nm;
  }
  if (l == 0) r[bm] = mx + __logf(s);
}

__global__ __launch_bounds__(256) void k_col_part(const float* __restrict__ l0,
                                                  const float* __restrict__ r,
                                                  float* __restrict__ pmax,
                                                  float* __restrict__ psum) {
  int t = threadIdx.x;
  int n = blockIdx.x * 256 + t;
  int p = blockIdx.y, b = blockIdx.z;
  const float* base = l0 + ((size_t)b * N + p * 32) * N + n;
  const float* rr = r + (size_t)b * N + p * 32;
  float mx = -1e30f, s = 0;
  for (int m = 0; m < 32; ++m) {
    float v = base[(size_t)m * N] - rr[m];
    if (v > mx) { s = s * __expf(mx - v) + 1.f; mx = v; }
    else s += __expf(v - mx);
  }
  pmax[((size_t)b * 32 + p) * N + n] = mx;
  psum[((size_t)b * 32 + p) * N + n] = s;
}

// ---------------------------------------------------------------- col finalize v2: 4-way p-split (R21, validated)
__global__ __launch_bounds__(256) void k_col_fin(const float* __restrict__ pmax,
                                                 const float* __restrict__ psum,
                                                 float* __restrict__ cvec) {
  __shared__ float smx[4][64], ssm[4][64];
  const int blk = blockIdx.x;            // 0..16*B-1
  const int b = blk >> 4;
  const int n0 = (blk & 15) * 64;
  const int tn = threadIdx.x & 63, tp = threadIdx.x >> 6;
  const int n = n0 + tn;
  float mx = -1e30f, s = 0.f;
#pragma unroll
  for (int pi = 0; pi < 8; ++pi) {
    int p = tp * 8 + pi;
    float m2 = pmax[((size_t)b * 32 + p) * N + n];
    float s2 = psum[((size_t)b * 32 + p) * N + n];
    float nm = fmaxf(mx, m2);
    s = s * __expf(mx - nm) + s2 * __expf(m2 - nm);
    mx = nm;
  }
  smx[tp][tn] = mx; ssm[tp][tn] = s;
  __syncthreads();
  if (tp == 0) {
#pragma unroll
    for (int q = 1; q < 4; ++q) {
      float m2 = smx[q][tn], s2 = ssm[q][tn];
      float nm = fmaxf(mx, m2);
      s = s * __expf(mx - nm) + s2 * __expf(m2 - nm);
      mx = nm;
    }
    cvec[(size_t)b * N + n] = mx + __logf(s);
  }
}

// ---------------------------------------------------------------- rodrigues + transform
__global__ __launch_bounds__(256) void k_rod(const float* __restrict__ pose,
                                             const float* __restrict__ p3d,
                                             float* __restrict__ p3dt) {
  int b = blockIdx.y;
  int n = blockIdx.x * 256 + threadIdx.x;
  const float* aa = pose + b * 6;
  float ax = aa[0], ay = aa[1], az = aa[2];
  float th = fmaxf(sqrtf(ax * ax + ay * ay + az * az), 1e-8f);
  float rx = ax / th, ry = ay / th, rz = az / th;
  float c = cosf(th), s = sinf(th), oc = 1.f - c;
  float R00 = c + oc * rx * rx,      R01 = oc * rx * ry - s * rz, R02 = oc * rx * rz + s * ry;
  float R10 = oc * ry * rx + s * rz, R11 = c + oc * ry * ry,      R12 = oc * ry * rz - s * rx;
  float R20 = oc * rz * rx - s * ry, R21 = oc * rz * ry + s * rx, R22 = c + oc * rz * rz;
  const float* p = p3d + ((size_t)b * N + n) * 3;
  float x = p[0], y = p[1], z = p[2];
  float X = R00 * x + R01 * y + R02 * z + aa[3];
  float Y = R10 * x + R11 * y + R12 * z + aa[4];
  float Z = R20 * x + R21 * y + R22 * z + aa[5];
  float inr = 1.f / sqrtf(X * X + Y * Y + Z * Z);
  float* o = p3dt + ((size_t)b * N + n) * 3;
  o[0] = X * inr; o[1] = Y * inr; o[2] = Z * inr;
}

// ---------------------------------------------------------------- final error (applies r,c offsets)
__global__ __launch_bounds__(256) void k_err(const float* __restrict__ l0,
                                             const float* __restrict__ r,
                                             const float* __restrict__ cvec,
                                             const float* __restrict__ f2,
                                             const float* __restrict__ p3dt,
                                             float* __restrict__ rowsum) {
  __shared__ float red[256];
  int m = blockIdx.x, b = blockIdx.y, t = threadIdx.x;
  const float* row = l0 + ((size_t)b * N + m) * N;
  const float* cl = cvec + (size_t)b * N;
  const float rm = r[(size_t)b * N + m];
  const float* f = f2 + ((size_t)b * N + m) * 3;
  float fx = f[0], fy = f[1], fz = f[2];
  float s = 0;
  for (int n = t; n < N; n += 256) {
    const float* pp = p3dt + ((size_t)b * N + n) * 3;
    float dot = fx * pp[0] + fy * pp[1] + fz * pp[2];
    s += __expf(row[n] - rm - cl[n]) * (1.f - dot);
  }
  red[t] = s; __syncthreads();
  for (int sft = 128; sft > 0; sft >>= 1) {
    if (t < sft) red[t] += red[t + sft];
    __syncthreads();
  }
  if (t == 0) rowsum[(size_t)b * N + m] = red[0];
}

__global__ __launch_bounds__(256) void k_err_fin(const float* __restrict__ rowsum,
                                                 float* __restrict__ out) {
  __shared__ float red[256];
  int b = blockIdx.x, t = threadIdx.x;
  float s = 0;
  for (int i = t; i < N; i += 256) s += rowsum[(size_t)b * N + i];
  red[t] = s; __syncthreads();
  for (int sft = 128; sft > 0; sft >>= 1) {
    if (t < sft) red[t] += red[t + sft];
    __syncthreads();
  }
  if (t == 0) out[b] = red[0];
}

// ================================================================= host
extern "C" void kernel_launch(void* const* d_in, const int* in_sizes, int n_in,
                              void* d_out, int out_size, void* d_ws, size_t ws_size,
                              hipStream_t stream) {
  const float* p2d     = (const float*)d_in[0];
  const float* p3d     = (const float*)d_in[1];
  const float* pose    = (const float*)d_in[2];
  const float* enc2d_w = (const float*)d_in[3];
  const float* enc2d_b = (const float*)d_in[4];
  const float* enc3d_w = (const float*)d_in[5];
  const float* enc3d_b = (const float*)d_in[6];
  const float* proj_w  = (const float*)d_in[7];
  const float* proj_b  = (const float*)d_in[8];
  const float* merge_w = (const float*)d_in[9];
  const float* merge_b = (const float*)d_in[10];
  const float* mlp1_w  = (const float*)d_in[11];
  const float* mlp1_b  = (const float*)d_in[12];
  const float* bn_g    = (const float*)d_in[13];
  const float* bn_b    = (const float*)d_in[14];
  const float* mlp2_w  = (const float*)d_in[15];
  const float* mlp2_b  = (const float*)d_in[16];

  float* W = (float*)d_ws;
  size_t off = 0;
  auto alloc = [&](size_t nelem) { float* p = W + off; off += nelem; return p; };
  const size_t SET = (size_t)B * D * N;
  float* f2    = alloc((size_t)B * N * 3);
  float* p3dt  = alloc((size_t)B * N * 3);
  float* descA = alloc(2 * SET);
  float* descB = alloc(2 * SET);
  float* qkv   = alloc(3 * 2 * SET);
  float* attnb = alloc(2 * SET);
  float* hb    = alloc((size_t)2 * B * 256 * N);
  float* stat  = alloc(2 * 256 * 2);
  float* pstat = alloc((size_t)2 * 256 * 32 * 2);
  float* la    = alloc((size_t)B * N * N);
  float* pmax  = alloc((size_t)B * 32 * N);
  float* psum  = alloc((size_t)B * 32 * N);
  float* cvec  = alloc((size_t)B * N);
  float* rvec  = alloc((size_t)B * N);
  float* rowsum= alloc((size_t)B * N);
  float* wcomb = alloc((size_t)6 * 256 * 256);
  float* bcomb = alloc((size_t)6 * 256);
  (void)ws_size; (void)in_sizes; (void)n_in; (void)out_size;

  float* Qb = qkv;
  float* Kb = qkv + 2 * SET;
  float* Vb = qkv + 4 * SET;
  const size_t DS = (size_t)D * N;

  k_fold<<<dim3(256, 6), 128, 0, stream>>>(mlp1_w, mlp1_b, merge_w, merge_b,
                                           wcomb, bcomb);

  k_norm2d<<<(B * N) / 256, 256, 0, stream>>>(p2d, f2);
  k_encode<<<dim3(N / 4, B), 256, 0, stream>>>(f2, enc2d_w, enc2d_b, descA);
  k_encode<<<dim3(N / 4, B), 256, 0, stream>>>(p3d, enc3d_w, enc3d_b, descA + SET);

  float* dc = descA;
  float* dn = descB;
  for (int i = 0; i < 6; ++i) {
    int cross = (i & 1);
    const float* pw = proj_w + (size_t)i * 3 * D * D;
    const float* pb = proj_b + (size_t)i * 3 * D;
    float* d0 = dc;
    float* d1 = dc + SET;
    const float* sA = cross ? d1 : d0;
    const float* sB = cross ? d0 : d1;

    k_gemm<<<dim3(64, 6), 256, 0, stream>>>(
        d0, d1, sA, sB, pw, pb, nullptr, qkv, nullptr, nullptr, nullptr,
        nullptr, D, D, DS, DS, D, 2 * SET, 1);
    k_attn<<<dim3(N / 128, NH, 2 * B), 512, 0, stream>>>(Qb, Kb, Vb, attnb);
    // mlp1 (merge folded) + fused BN partial stats
    k_gemm<<<dim3(64, 4), 256, 0, stream>>>(
        dc, dc + SET, attnb, attnb + SET, wcomb + (size_t)i * 256 * 256,
        bcomb + (size_t)i * 256, nullptr, hb, nullptr, nullptr, nullptr,
        pstat, 256, 128, DS, DS, 256, 0, 0);
    k_bnstat_c<<<2, 256, 0, stream>>>(pstat, stat);
    k_gemm<<<dim3(64, 2), 256, 0, stream>>>(
        hb, hb + (size_t)B * 256 * N, nullptr, nullptr,
        mlp2_w + (size_t)i * D * 256, mlp2_b + (size_t)i * D, dc, dn,
        stat, bn_g + (size_t)i * 256, bn_b + (size_t)i * 256,
        nullptr, 256, 256, (size_t)256 * N, 0, D, 0, 0);
    float* tmp = dc; dc = dn; dn = tmp;
  }

  k_dist<<<dim3(N / 8, B), 256, 0, stream>>>(dc, dc + SET, la);
  for (int it = 0; it < 10; ++it) {
    k_row_r<<<(B * N) / 4, 256, 0, stream>>>(la, cvec, rvec, it > 0 ? 1 : 0);
    k_col_part<<<dim3(N / 256, 32, B), 256, 0, stream>>>(la, rvec, pmax, psum);
    k_col_fin<<<16 * B, 256, 0, stream>>>(pmax, psum, cvec);
  }
  k_rod<<<dim3(N / 256, B), 256, 0, stream>>>(pose, p3d, p3dt);
  k_err<<<dim3(N, B), 256, 0, stream>>>(la, rvec, cvec, f2, p3dt, rowsum);
  k_err_fin<<<B, 256, 0, stream>>>(rowsum, (float*)d_out);
}